// Round 1
// baseline (450.577 us; speedup 1.0000x reference)
//
#include <hip/hip_runtime.h>
#include <cmath>

// Problem constants
#define BB 64
#define TT 128
#define SS 512
#define EE 1024
#define DDIM 512
#define NEG_INF_F (-1.0e10f)

// MFMA tiling: block 128x64, K-tile 32, 4 waves (2x2), wave tile 64x32
#define BM 128
#define BN 64
#define BK 32
#define LDSTP 20   // padded layout row stride (dwords): 80 B rows -> b128-aligned, 2-way banks (free)
#define ROWU 32    // swizzled plane layout row stride in u16 (64 B/row)

typedef unsigned short u16;
typedef __attribute__((ext_vector_type(8))) short bf16x8;
typedef __attribute__((ext_vector_type(4))) float f32x4;

// ---------------------------------------------------------------------------
// fp32 -> bf16 split (hi = rne(f), lo = rne(f - hi)); ~2^-18 rel error
// ---------------------------------------------------------------------------
__device__ __forceinline__ unsigned bf16_rne(float f) {
    unsigned u = __float_as_uint(f);
    return (u + 0x7fffu + ((u >> 16) & 1u)) >> 16;
}
__device__ __forceinline__ void split2(float f, unsigned& h, unsigned& l) {
    h = bf16_rne(f);
    float fh = __uint_as_float(h << 16);
    l = bf16_rne(f - fh);
}

// ---------------------------------------------------------------------------
// glds staging of a bf16 plane tile: ROWS rows x 32 bf16 (64 B/row), with the
// quad-swizzle chunk(q)->slot q^((r>>1)&3). Lane-linear LDS writes (16 B/lane).
// src points at (row0, k0) of a plane with row stride ld (u16 elems).
// ---------------------------------------------------------------------------
template <int ROWS>
__device__ __forceinline__ void stage_glds(u16* lds, const u16* __restrict__ src,
                                           int ld, int tid) {
    const int w = tid >> 6, lane = tid & 63;
    const int rl = lane >> 2, p = lane & 3;
#pragma unroll
    for (int i = 0; i < ROWS / 64; ++i) {
        const int r0 = (w + 4 * i) * 16;
        const int r = r0 + rl;
        const int q = p ^ ((r >> 1) & 3);
        const u16* g = src + (size_t)r * ld + 8 * q;
        __builtin_amdgcn_global_load_lds(
            (const __attribute__((address_space(1))) unsigned*)g,
            (__attribute__((address_space(3))) unsigned*)(lds + r0 * ROWU),
            16, 0, 0);
    }
}

// Read a 16x16x32 fragment from the swizzled plane layout (one ds_read_b128)
__device__ __forceinline__ bf16x8 read_frag_sw(const u16* buf, int row, int q) {
    const int c = q ^ ((row >> 1) & 3);
    return *(const bf16x8*)(buf + row * ROWU + 8 * c);
}

// ---------------------------------------------------------------------------
// Split staging of an NT fp32 operand (64 rows x BK, k contiguous):
// load phase (global float4 -> regs) and store phase (split2 -> padded LDS).
// ---------------------------------------------------------------------------
__device__ __forceinline__ void stage_nt_load(float4* v, const float* __restrict__ src,
                                              int ld, int tid) {
#pragma unroll
    for (int i = 0; i < 2; ++i) {
        int s = tid + 256 * i;
        int r = s >> 3, kq = s & 7;
        v[i] = *(const float4*)(src + (size_t)r * ld + 4 * kq);
    }
}
__device__ __forceinline__ void stage_nt_store(unsigned* hi, unsigned* lo,
                                               const float4* v, int tid) {
#pragma unroll
    for (int i = 0; i < 2; ++i) {
        int s = tid + 256 * i;
        int r = s >> 3, kq = s & 7;
        unsigned h0, l0, h1, l1, h2, l2, h3, l3;
        split2(v[i].x, h0, l0); split2(v[i].y, h1, l1);
        split2(v[i].z, h2, l2); split2(v[i].w, h3, l3);
        *(uint2*)&hi[r * LDSTP + 2 * kq] = make_uint2(h0 | (h1 << 16), h2 | (h3 << 16));
        *(uint2*)&lo[r * LDSTP + 2 * kq] = make_uint2(l0 | (l1 << 16), l2 | (l3 << 16));
    }
}

// ---------------------------------------------------------------------------
// Split staging of a transposed fp32 B tile for NN GEMM (k_ctx): global
// [BK rows k][BN cols n] -> padded LDS rows = n. src at (k0, n0), ld = row stride.
// ---------------------------------------------------------------------------
__device__ __forceinline__ void stage_tr_load(float4* v, const float* __restrict__ src,
                                              int ld, int tid) {
    int eq = tid & 15;   // n quad
    int sp = tid >> 4;   // k pair
    const float* p = src + (size_t)(2 * sp) * ld + 4 * eq;
    v[0] = *(const float4*)p;
    v[1] = *(const float4*)(p + ld);
}
__device__ __forceinline__ void stage_tr_store(unsigned* hi, unsigned* lo,
                                               const float4* v, int tid) {
    int eq = tid & 15;
    int sp = tid >> 4;
    float av[4] = {v[0].x, v[0].y, v[0].z, v[0].w};
    float bv[4] = {v[1].x, v[1].y, v[1].z, v[1].w};
#pragma unroll
    for (int c = 0; c < 4; ++c) {
        unsigned ha, la, hb, lb;
        split2(av[c], ha, la);
        split2(bv[c], hb, lb);
        hi[(4 * eq + c) * LDSTP + sp] = ha | (hb << 16);
        lo[(4 * eq + c) * LDSTP + sp] = la | (lb << 16);
    }
}

// Read a fragment from the padded layout (aligned b128: 80r+16q bytes)
__device__ __forceinline__ bf16x8 read_frag_pad(const unsigned* buf, int row, int q) {
    return *(const bf16x8*)(buf + row * LDSTP + 4 * q);
}

// ---------------------------------------------------------------------------
// Split-bf16 MFMA cores (3 MFMAs per 16x16 tile: AhBh + AhBl + AlBh)
// ---------------------------------------------------------------------------
__device__ __forceinline__ void mfma_ss(const u16* Ah, const u16* Al,
                                        const u16* Bh, const u16* Bl,
                                        f32x4 acc[4][2], int tid) {
    const int lane = tid & 63, w = tid >> 6;
    const int wm = (w & 1) * 64, wn = (w >> 1) * 32;
    const int fr = lane & 15, q = lane >> 4;
    bf16x8 ah[4], al[4];
#pragma unroll
    for (int i = 0; i < 4; ++i) {
        ah[i] = read_frag_sw(Ah, wm + 16 * i + fr, q);
        al[i] = read_frag_sw(Al, wm + 16 * i + fr, q);
    }
#pragma unroll
    for (int j = 0; j < 2; ++j) {
        bf16x8 bh = read_frag_sw(Bh, wn + 16 * j + fr, q);
        bf16x8 bl = read_frag_sw(Bl, wn + 16 * j + fr, q);
#pragma unroll
        for (int i = 0; i < 4; ++i) {
            acc[i][j] = __builtin_amdgcn_mfma_f32_16x16x32_bf16(ah[i], bh, acc[i][j], 0, 0, 0);
            acc[i][j] = __builtin_amdgcn_mfma_f32_16x16x32_bf16(ah[i], bl, acc[i][j], 0, 0, 0);
            acc[i][j] = __builtin_amdgcn_mfma_f32_16x16x32_bf16(al[i], bh, acc[i][j], 0, 0, 0);
        }
    }
}

__device__ __forceinline__ void mfma_sp(const u16* Ah, const u16* Al,
                                        const unsigned* Bh, const unsigned* Bl,
                                        f32x4 acc[4][2], int tid) {
    const int lane = tid & 63, w = tid >> 6;
    const int wm = (w & 1) * 64, wn = (w >> 1) * 32;
    const int fr = lane & 15, q = lane >> 4;
    bf16x8 ah[4], al[4];
#pragma unroll
    for (int i = 0; i < 4; ++i) {
        ah[i] = read_frag_sw(Ah, wm + 16 * i + fr, q);
        al[i] = read_frag_sw(Al, wm + 16 * i + fr, q);
    }
#pragma unroll
    for (int j = 0; j < 2; ++j) {
        bf16x8 bh = read_frag_pad(Bh, wn + 16 * j + fr, q);
        bf16x8 bl = read_frag_pad(Bl, wn + 16 * j + fr, q);
#pragma unroll
        for (int i = 0; i < 4; ++i) {
            acc[i][j] = __builtin_amdgcn_mfma_f32_16x16x32_bf16(ah[i], bh, acc[i][j], 0, 0, 0);
            acc[i][j] = __builtin_amdgcn_mfma_f32_16x16x32_bf16(ah[i], bl, acc[i][j], 0, 0, 0);
            acc[i][j] = __builtin_amdgcn_mfma_f32_16x16x32_bf16(al[i], bh, acc[i][j], 0, 0, 0);
        }
    }
}

// ---------------------------------------------------------------------------
// Convert kernels
// ---------------------------------------------------------------------------
__global__ __launch_bounds__(256) void k_conv(const float* __restrict__ src,
                                              u16* __restrict__ hi, u16* __restrict__ lo) {
    const int i = blockIdx.x * 256 + threadIdx.x;
    float4 v = ((const float4*)src)[i];
    unsigned h0, l0, h1, l1, h2, l2, h3, l3;
    split2(v.x, h0, l0); split2(v.y, h1, l1);
    split2(v.z, h2, l2); split2(v.w, h3, l3);
    ((ushort4*)hi)[i] = make_ushort4((u16)h0, (u16)h1, (u16)h2, (u16)h3);
    ((ushort4*)lo)[i] = make_ushort4((u16)l0, (u16)l1, (u16)l2, (u16)l3);
}

// Wo [1536,512] -> WoT planes [512,1536]
__global__ __launch_bounds__(256) void k_wot(const float* __restrict__ Wo,
                                             u16* __restrict__ thi, u16* __restrict__ tlo) {
    __shared__ float t[64][65];
    const int tid = threadIdx.x;
    const int r0 = blockIdx.x * 64;  // Wo row tile (k)
    const int c0 = blockIdx.y * 64;  // Wo col tile (n)
    const int rr = tid >> 4, cc = tid & 15;
#pragma unroll
    for (int i = 0; i < 4; ++i) {
        float4 v = *(const float4*)(Wo + (size_t)(r0 + rr + 16 * i) * DDIM + c0 + 4 * cc);
        t[rr + 16 * i][4 * cc + 0] = v.x;
        t[rr + 16 * i][4 * cc + 1] = v.y;
        t[rr + 16 * i][4 * cc + 2] = v.z;
        t[rr + 16 * i][4 * cc + 3] = v.w;
    }
    __syncthreads();
#pragma unroll
    for (int i = 0; i < 4; ++i) {
        const int oc = rr + 16 * i;  // WoT row (= Wo col)
        unsigned h0, l0, h1, l1, h2, l2, h3, l3;
        split2(t[4 * cc + 0][oc], h0, l0);
        split2(t[4 * cc + 1][oc], h1, l1);
        split2(t[4 * cc + 2][oc], h2, l2);
        split2(t[4 * cc + 3][oc], h3, l3);
        size_t off = (size_t)(c0 + oc) * (EE + DDIM) + r0 + 4 * cc;
        *(ushort4*)(thi + off) = make_ushort4((u16)h0, (u16)h1, (u16)h2, (u16)h3);
        *(ushort4*)(tlo + off) = make_ushort4((u16)l0, (u16)l1, (u16)l2, (u16)l3);
    }
}

// ---------------------------------------------------------------------------
// K1: decW = dec @ W_attn^T (NT, M=8192, N=1024, K=512) -> hi/lo planes
// 2-phase pipelined: prefetch K-tile t+1 (glds) while MFMAing tile t.
// ---------------------------------------------------------------------------
__global__ __launch_bounds__(256) void k_decw(const u16* __restrict__ Ahp, const u16* __restrict__ Alp,
                                              const u16* __restrict__ Bhp, const u16* __restrict__ Blp,
                                              u16* __restrict__ Chi, u16* __restrict__ Clo) {
    __shared__ u16 Ah[2][BM * ROWU], Al[2][BM * ROWU], Bh[2][BN * ROWU], Bl[2][BN * ROWU];
    const int tid = threadIdx.x;
    const int bm = blockIdx.x * BM, bn = blockIdx.y * BN;  // x = m for B-tile L2 reuse
    const u16* Ahs = Ahp + (size_t)bm * DDIM;
    const u16* Als = Alp + (size_t)bm * DDIM;
    const u16* Bhs = Bhp + (size_t)bn * DDIM;
    const u16* Bls = Blp + (size_t)bn * DDIM;
    f32x4 acc[4][2] = {};
    // prologue: stage tile 0
    stage_glds<BM>(Ah[0], Ahs, DDIM, tid);
    stage_glds<BM>(Al[0], Als, DDIM, tid);
    stage_glds<BN>(Bh[0], Bhs, DDIM, tid);
    stage_glds<BN>(Bl[0], Bls, DDIM, tid);
    __builtin_amdgcn_s_waitcnt(0);
    __syncthreads();
    int cur = 0;
    for (int k0 = BK; k0 < DDIM; k0 += BK) {
        stage_glds<BM>(Ah[cur ^ 1], Ahs + k0, DDIM, tid);
        stage_glds<BM>(Al[cur ^ 1], Als + k0, DDIM, tid);
        stage_glds<BN>(Bh[cur ^ 1], Bhs + k0, DDIM, tid);
        stage_glds<BN>(Bl[cur ^ 1], Bls + k0, DDIM, tid);
        mfma_ss(Ah[cur], Al[cur], Bh[cur], Bl[cur], acc, tid);
        __builtin_amdgcn_s_waitcnt(0);
        __syncthreads();
        cur ^= 1;
    }
    mfma_ss(Ah[cur], Al[cur], Bh[cur], Bl[cur], acc, tid);
    const int lane = tid & 63, w = tid >> 6;
    const int wm = (w & 1) * 64, wn = (w >> 1) * 32;
    const int fr = lane & 15, q = lane >> 4;
#pragma unroll
    for (int j = 0; j < 2; ++j) {
        const int col = bn + wn + 16 * j + fr;
#pragma unroll
        for (int i = 0; i < 4; ++i)
#pragma unroll
            for (int r = 0; r < 4; ++r) {
                const int row = bm + wm + 16 * i + 4 * q + r;
                unsigned h, l;
                split2(acc[i][j][r], h, l);
                Chi[(size_t)row * EE + col] = (u16)h;
                Clo[(size_t)row * EE + col] = (u16)l;
            }
    }
}

// ---------------------------------------------------------------------------
// K1b: decb[m] = dec[m,:] . b_attn
// ---------------------------------------------------------------------------
__global__ __launch_bounds__(256) void k_decb(const float* __restrict__ dec,
                                              const float* __restrict__ ba,
                                              float* __restrict__ decb) {
    const int row = blockIdx.x * 4 + (threadIdx.x >> 6);
    const int lane = threadIdx.x & 63;
    const float* x = dec + (size_t)row * DDIM;
    float s = 0.f;
#pragma unroll
    for (int i = 0; i < 8; ++i) {
        int idx = lane + i * 64;
        s += x[idx] * ba[idx];
    }
#pragma unroll
    for (int off = 32; off >= 1; off >>= 1) s += __shfl_xor(s, off, 64);
    if (lane == 0) decb[row] = s;
}

// ---------------------------------------------------------------------------
// K2: masked energies (NT batched, M=T=128, N=S, K=E) + bias + mask
// 2-phase pipelined; enc staged via T14 split (load regs early, convert late).
// ---------------------------------------------------------------------------
__global__ __launch_bounds__(256) void k_energy(const u16* __restrict__ Ahp, const u16* __restrict__ Alp,
                                                const float* __restrict__ enc,
                                                const int* __restrict__ mask,
                                                const float* __restrict__ decb,
                                                float* __restrict__ menerg) {
    const int b = blockIdx.z;
    const int bn = blockIdx.x * BN;
    __shared__ u16 Ah[2][BM * ROWU], Al[2][BM * ROWU];
    __shared__ unsigned Bh[2][BN * LDSTP], Bl[2][BN * LDSTP];
    const int tid = threadIdx.x;
    const u16* Abh = Ahp + (size_t)b * TT * EE;
    const u16* Abl = Alp + (size_t)b * TT * EE;
    const float* Bt = enc + (size_t)b * SS * EE + (size_t)bn * EE;
    f32x4 acc[4][2] = {};
    float4 bv[2];
    // prologue: stage tile 0
    stage_glds<BM>(Ah[0], Abh, EE, tid);
    stage_glds<BM>(Al[0], Abl, EE, tid);
    stage_nt_load(bv, Bt, EE, tid);
    stage_nt_store(Bh[0], Bl[0], bv, tid);
    __builtin_amdgcn_s_waitcnt(0);
    __syncthreads();
    int cur = 0;
    for (int k0 = BK; k0 < EE; k0 += BK) {
        stage_nt_load(bv, Bt + k0, EE, tid);           // fp32 loads for t+1, in flight
        stage_glds<BM>(Ah[cur ^ 1], Abh + k0, EE, tid);
        stage_glds<BM>(Al[cur ^ 1], Abl + k0, EE, tid);
        mfma_sp(Ah[cur], Al[cur], Bh[cur], Bl[cur], acc, tid);
        stage_nt_store(Bh[cur ^ 1], Bl[cur ^ 1], bv, tid);  // convert+write after MFMA
        __builtin_amdgcn_s_waitcnt(0);
        __syncthreads();
        cur ^= 1;
    }
    mfma_sp(Ah[cur], Al[cur], Bh[cur], Bl[cur], acc, tid);
    const int lane = tid & 63, w = tid >> 6;
    const int wm = (w & 1) * 64, wn = (w >> 1) * 32;
    const int fr = lane & 15, q = lane >> 4;
    const int* mb = mask + (size_t)b * SS;
    const float* dbp = decb + (size_t)b * TT;
    float* Crow = menerg + (size_t)b * TT * SS;
    float db[4][4];
#pragma unroll
    for (int i = 0; i < 4; ++i) {
        float4 d4 = *(const float4*)(dbp + wm + 16 * i + 4 * q);
        db[i][0] = d4.x; db[i][1] = d4.y; db[i][2] = d4.z; db[i][3] = d4.w;
    }
#pragma unroll
    for (int j = 0; j < 2; ++j) {
        const int col = bn + wn + 16 * j + fr;
        const int mk = mb[col];
#pragma unroll
        for (int i = 0; i < 4; ++i)
#pragma unroll
            for (int r = 0; r < 4; ++r) {
                const int row = wm + 16 * i + 4 * q + r;
                Crow[(size_t)row * SS + col] = mk ? acc[i][j][r] + db[i][r] : NEG_INF_F;
            }
    }
}

// ---------------------------------------------------------------------------
// K3: softmax over S=512 -> attn fp32 (output) + attn hi/lo planes
// ---------------------------------------------------------------------------
__global__ __launch_bounds__(128) void k_softmax(const float* __restrict__ me,
                                                 float* __restrict__ attn,
                                                 u16* __restrict__ ahi,
                                                 u16* __restrict__ alo) {
    const int row = blockIdx.x;
    const int tid = threadIdx.x;
    const float4 v = ((const float4*)(me + (size_t)row * SS))[tid];
    float m = fmaxf(fmaxf(v.x, v.y), fmaxf(v.z, v.w));
#pragma unroll
    for (int off = 32; off >= 1; off >>= 1) m = fmaxf(m, __shfl_xor(m, off, 64));
    __shared__ float redm[2];
    __shared__ float reds[2];
    const int wv = tid >> 6, lane = tid & 63;
    if (lane == 0) redm[wv] = m;
    __syncthreads();
    m = fmaxf(redm[0], redm[1]);
    float e0 = __expf(v.x - m), e1 = __expf(v.y - m);
    float e2 = __expf(v.z - m), e3 = __expf(v.w - m);
    float s = (e0 + e1) + (e2 + e3);
#pragma unroll
    for (int off = 32; off >= 1; off >>= 1) s += __shfl_xor(s, off, 64);
    if (lane == 0) reds[wv] = s;
    __syncthreads();
    s = reds[0] + reds[1];
    const float inv = 1.0f / s;
    float o0 = e0 * inv, o1 = e1 * inv, o2 = e2 * inv, o3 = e3 * inv;
    ((float4*)(attn + (size_t)row * SS))[tid] = make_float4(o0, o1, o2, o3);
    unsigned h0, l0, h1, l1, h2, l2, h3, l3;
    split2(o0, h0, l0); split2(o1, h1, l1); split2(o2, h2, l2); split2(o3, h3, l3);
    ((ushort4*)(ahi + (size_t)row * SS))[tid] = make_ushort4((u16)h0, (u16)h1, (u16)h2, (u16)h3);
    ((ushort4*)(alo + (size_t)row * SS))[tid] = make_ushort4((u16)l0, (u16)l1, (u16)l2, (u16)l3);
}

// ---------------------------------------------------------------------------
// K4: wc = attn @ enc (NN batched, M=T, N=E, K=S) -> wc hi/lo planes
// 2-phase pipelined; enc^T staged via T14 split.
// ---------------------------------------------------------------------------
__global__ __launch_bounds__(256) void k_ctx(const u16* __restrict__ Ahp, const u16* __restrict__ Alp,
                                             const float* __restrict__ enc,
                                             u16* __restrict__ Chi, u16* __restrict__ Clo) {
    const int b = blockIdx.z;
    const int bn = blockIdx.x * BN;  // over E
    __shared__ u16 Ah[2][BM * ROWU], Al[2][BM * ROWU];
    __shared__ unsigned Bh[2][BN * LDSTP], Bl[2][BN * LDSTP];
    const int tid = threadIdx.x;
    const u16* Abh = Ahp + (size_t)b * TT * SS;
    const u16* Abl = Alp + (size_t)b * TT * SS;
    const float* Bm = enc + (size_t)b * SS * EE + bn;
    f32x4 acc[4][2] = {};
    float4 bv[2];
    // prologue: stage tile 0
    stage_glds<BM>(Ah[0], Abh, SS, tid);
    stage_glds<BM>(Al[0], Abl, SS, tid);
    stage_tr_load(bv, Bm, EE, tid);
    stage_tr_store(Bh[0], Bl[0], bv, tid);
    __builtin_amdgcn_s_waitcnt(0);
    __syncthreads();
    int cur = 0;
    for (int k0 = BK; k0 < SS; k0 += BK) {
        stage_tr_load(bv, Bm + (size_t)k0 * EE, EE, tid);   // fp32 loads for t+1
        stage_glds<BM>(Ah[cur ^ 1], Abh + k0, SS, tid);
        stage_glds<BM>(Al[cur ^ 1], Abl + k0, SS, tid);
        mfma_sp(Ah[cur], Al[cur], Bh[cur], Bl[cur], acc, tid);
        stage_tr_store(Bh[cur ^ 1], Bl[cur ^ 1], bv, tid);  // convert+write after MFMA
        __builtin_amdgcn_s_waitcnt(0);
        __syncthreads();
        cur ^= 1;
    }
    mfma_sp(Ah[cur], Al[cur], Bh[cur], Bl[cur], acc, tid);
    const int lane = tid & 63, w = tid >> 6;
    const int wm = (w & 1) * 64, wn = (w >> 1) * 32;
    const int fr = lane & 15, q = lane >> 4;
    u16* Ch = Chi + (size_t)b * TT * EE;
    u16* Cl = Clo + (size_t)b * TT * EE;
#pragma unroll
    for (int j = 0; j < 2; ++j) {
        const int col = bn + wn + 16 * j + fr;
#pragma unroll
        for (int i = 0; i < 4; ++i)
#pragma unroll
            for (int r = 0; r < 4; ++r) {
                const int row = wm + 16 * i + 4 * q + r;
                unsigned h, l;
                split2(acc[i][j][r], h, l);
                Ch[(size_t)row * EE + col] = (u16)h;
                Cl[(size_t)row * EE + col] = (u16)l;
            }
    }
}

// ---------------------------------------------------------------------------
// K5: h_tilde = tanh([wc | dec] @ W_out) via WoT planes (NT, M=8192, N=512, K=1536)
// 2-phase pipelined (all-glds staging).
// ---------------------------------------------------------------------------
__global__ __launch_bounds__(256) void k_out(const u16* __restrict__ wch, const u16* __restrict__ wcl,
                                             const u16* __restrict__ dech, const u16* __restrict__ decl,
                                             const u16* __restrict__ woth, const u16* __restrict__ wotl,
                                             float* __restrict__ ht) {
    __shared__ u16 Ah[2][BM * ROWU], Al[2][BM * ROWU], Bh[2][BN * ROWU], Bl[2][BN * ROWU];
    const int tid = threadIdx.x;
    const int bm = blockIdx.x * BM, bn = blockIdx.y * BN;  // x = m for B-tile reuse
    const int KTOT = EE + DDIM;
    f32x4 acc[4][2] = {};
    // prologue: stage tile 0 (k0 = 0 < EE, always wc)
    stage_glds<BM>(Ah[0], wch + (size_t)bm * EE, EE, tid);
    stage_glds<BM>(Al[0], wcl + (size_t)bm * EE, EE, tid);
    stage_glds<BN>(Bh[0], woth + (size_t)bn * KTOT, KTOT, tid);
    stage_glds<BN>(Bl[0], wotl + (size_t)bn * KTOT, KTOT, tid);
    __builtin_amdgcn_s_waitcnt(0);
    __syncthreads();
    int cur = 0;
    for (int k0 = BK; k0 < KTOT; k0 += BK) {
        const u16 *ah, *al;
        int ld;
        if (k0 < EE) {
            ah = wch + (size_t)bm * EE + k0;
            al = wcl + (size_t)bm * EE + k0;
            ld = EE;
        } else {
            ah = dech + (size_t)bm * DDIM + (k0 - EE);
            al = decl + (size_t)bm * DDIM + (k0 - EE);
            ld = DDIM;
        }
        stage_glds<BM>(Ah[cur ^ 1], ah, ld, tid);
        stage_glds<BM>(Al[cur ^ 1], al, ld, tid);
        stage_glds<BN>(Bh[cur ^ 1], woth + (size_t)bn * KTOT + k0, KTOT, tid);
        stage_glds<BN>(Bl[cur ^ 1], wotl + (size_t)bn * KTOT + k0, KTOT, tid);
        mfma_ss(Ah[cur], Al[cur], Bh[cur], Bl[cur], acc, tid);
        __builtin_amdgcn_s_waitcnt(0);
        __syncthreads();
        cur ^= 1;
    }
    mfma_ss(Ah[cur], Al[cur], Bh[cur], Bl[cur], acc, tid);
    const int lane = tid & 63, w = tid >> 6;
    const int wm = (w & 1) * 64, wn = (w >> 1) * 32;
    const int fr = lane & 15, q = lane >> 4;
#pragma unroll
    for (int j = 0; j < 2; ++j) {
        const int col = bn + wn + 16 * j + fr;
#pragma unroll
        for (int i = 0; i < 4; ++i)
#pragma unroll
            for (int r = 0; r < 4; ++r) {
                const int row = bm + wm + 16 * i + 4 * q + r;
                ht[(size_t)row * DDIM + col] = tanhf(acc[i][j][r]);
            }
    }
}

// ---------------------------------------------------------------------------
extern "C" void kernel_launch(void* const* d_in, const int* in_sizes, int n_in,
                              void* d_out, int out_size, void* d_ws, size_t ws_size,
                              hipStream_t stream) {
    (void)in_sizes; (void)n_in; (void)out_size; (void)ws_size;
    const float* dec = (const float*)d_in[0];
    const float* enc = (const float*)d_in[1];
    const int* mask = (const int*)d_in[2];
    const float* Wa = (const float*)d_in[3];
    const float* ba = (const float*)d_in[4];
    const float* Wo = (const float*)d_in[5];

    float* h_tilde = (float*)d_out;
    float* attn = h_tilde + (size_t)BB * TT * DDIM;
    float* menerg = attn + (size_t)BB * TT * SS;

    // Workspace layout (bytes), total ~72.4 MB
    char* ws = (char*)d_ws;
    u16* decW_hi = (u16*)(ws);                       // 8192x1024 u16 = 16.78 MB
    u16* decW_lo = (u16*)(ws + 16777216);
    u16* dec_hi  = (u16*)(ws + 33554432);            // 8192x512
    u16* dec_lo  = (u16*)(ws + 41943040);
    u16* attn_hi = (u16*)(ws + 50331648);            // 8192x512
    u16* attn_lo = (u16*)(ws + 58720256);
    u16* wa_hi   = (u16*)(ws + 67108864);            // 1024x512
    u16* wa_lo   = (u16*)(ws + 68157440);
    u16* wot_hi  = (u16*)(ws + 69206016);            // 512x1536
    u16* wot_lo  = (u16*)(ws + 70778880);
    float* decb  = (float*)(ws + 72351744);          // 8192 f32
    // wc planes alias decW planes (decW dead after k_energy)
    u16* wc_hi = decW_hi;
    u16* wc_lo = decW_lo;

    k_conv<<<(BB * TT * DDIM) / 4 / 256, 256, 0, stream>>>(dec, dec_hi, dec_lo);
    k_conv<<<(EE * DDIM) / 4 / 256, 256, 0, stream>>>(Wa, wa_hi, wa_lo);
    k_wot<<<dim3((EE + DDIM) / 64, DDIM / 64), 256, 0, stream>>>(Wo, wot_hi, wot_lo);
    k_decb<<<(BB * TT) / 4, 256, 0, stream>>>(dec, ba, decb);
    k_decw<<<dim3((BB * TT) / BM, EE / BN), 256, 0, stream>>>(dec_hi, dec_lo, wa_hi, wa_lo,
                                                              decW_hi, decW_lo);
    k_energy<<<dim3(SS / BN, 1, BB), 256, 0, stream>>>(decW_hi, decW_lo, enc, mask, decb, menerg);
    k_softmax<<<BB * TT, 128, 0, stream>>>(menerg, attn, attn_hi, attn_lo);
    k_ctx<<<dim3(EE / BN, 1, BB), 256, 0, stream>>>(attn_hi, attn_lo, enc, wc_hi, wc_lo);
    k_out<<<dim3((BB * TT) / BM, DDIM / BN), 256, 0, stream>>>(wc_hi, wc_lo, dec_hi, dec_lo,
                                                               wot_hi, wot_lo, h_tilde);
}

// Round 2
// 413.215 us; speedup vs baseline: 1.0904x; 1.0904x over previous
//
#include <hip/hip_runtime.h>
#include <cmath>

// Problem constants
#define BB 64
#define TT 128
#define SS 512
#define EE 1024
#define DDIM 512
#define NEG_INF_F (-1.0e10f)

// MFMA tiling: block 128x64, K-tile 32, 4 waves (2x2), wave tile 64x32
#define BM 128
#define BM2 64   // half-height block for grid-limited kernels (wave tile 32x32)
#define BN 64
#define BK 32
#define LDSTP 20   // padded layout row stride (dwords): 80 B rows -> b128-aligned, 2-way banks (free)
#define ROWU 32    // swizzled plane layout row stride in u16 (64 B/row)

typedef unsigned short u16;
typedef __attribute__((ext_vector_type(8))) short bf16x8;
typedef __attribute__((ext_vector_type(4))) float f32x4;

// ---------------------------------------------------------------------------
// fp32 -> bf16 split (hi = rne(f), lo = rne(f - hi)); ~2^-18 rel error
// ---------------------------------------------------------------------------
__device__ __forceinline__ unsigned bf16_rne(float f) {
    unsigned u = __float_as_uint(f);
    return (u + 0x7fffu + ((u >> 16) & 1u)) >> 16;
}
__device__ __forceinline__ void split2(float f, unsigned& h, unsigned& l) {
    h = bf16_rne(f);
    float fh = __uint_as_float(h << 16);
    l = bf16_rne(f - fh);
}

// ---------------------------------------------------------------------------
// glds staging of a bf16 plane tile: ROWS rows x 32 bf16 (64 B/row), with the
// quad-swizzle chunk(q)->slot q^((r>>1)&3). Lane-linear LDS writes (16 B/lane).
// src points at (row0, k0) of a plane with row stride ld (u16 elems).
// ---------------------------------------------------------------------------
template <int ROWS>
__device__ __forceinline__ void stage_glds(u16* lds, const u16* __restrict__ src,
                                           int ld, int tid) {
    const int w = tid >> 6, lane = tid & 63;
    const int rl = lane >> 2, p = lane & 3;
#pragma unroll
    for (int i = 0; i < ROWS / 64; ++i) {
        const int r0 = (w + 4 * i) * 16;
        const int r = r0 + rl;
        const int q = p ^ ((r >> 1) & 3);
        const u16* g = src + (size_t)r * ld + 8 * q;
        __builtin_amdgcn_global_load_lds(
            (const __attribute__((address_space(1))) unsigned*)g,
            (__attribute__((address_space(3))) unsigned*)(lds + r0 * ROWU),
            16, 0, 0);
    }
}

// Read a 16x16x32 fragment from the swizzled plane layout (one ds_read_b128)
__device__ __forceinline__ bf16x8 read_frag_sw(const u16* buf, int row, int q) {
    const int c = q ^ ((row >> 1) & 3);
    return *(const bf16x8*)(buf + row * ROWU + 8 * c);
}

// ---------------------------------------------------------------------------
// VALU staging of an NT fp32 operand (rows x BK, k contiguous) into padded
// hi/lo LDS (u32 = bf16 pair (2k,2k+1)). Used for enc in k_energy.
// ---------------------------------------------------------------------------
template <int ROWS>
__device__ __forceinline__ void stage_nt(unsigned* hi, unsigned* lo,
                                         const float* __restrict__ src, int ld, int tid) {
#pragma unroll
    for (int i = 0; i < ROWS / 32; ++i) {
        int s = tid + 256 * i;
        int r = s >> 3, kq = s & 7;
        float4 v = *(const float4*)(src + (size_t)r * ld + 4 * kq);
        unsigned h0, l0, h1, l1, h2, l2, h3, l3;
        split2(v.x, h0, l0); split2(v.y, h1, l1);
        split2(v.z, h2, l2); split2(v.w, h3, l3);
        *(uint2*)&hi[r * LDSTP + 2 * kq] = make_uint2(h0 | (h1 << 16), h2 | (h3 << 16));
        *(uint2*)&lo[r * LDSTP + 2 * kq] = make_uint2(l0 | (l1 << 16), l2 | (l3 << 16));
    }
}

// ---------------------------------------------------------------------------
// VALU staging of a transposed fp32 B tile for NN GEMM (k_ctx): global
// [BK rows k][BN cols n] -> padded LDS rows = n. src at (k0, n0), ld = row stride.
// ---------------------------------------------------------------------------
__device__ __forceinline__ void stage_tr(unsigned* hi, unsigned* lo,
                                         const float* __restrict__ src, int ld, int tid) {
    int eq = tid & 15;   // n quad
    int sp = tid >> 4;   // k pair
    const float* p = src + (size_t)(2 * sp) * ld + 4 * eq;
    float4 va = *(const float4*)p;
    float4 vb = *(const float4*)(p + ld);
    float av[4] = {va.x, va.y, va.z, va.w};
    float bv[4] = {vb.x, vb.y, vb.z, vb.w};
#pragma unroll
    for (int c = 0; c < 4; ++c) {
        unsigned ha, la, hb, lb;
        split2(av[c], ha, la);
        split2(bv[c], hb, lb);
        hi[(4 * eq + c) * LDSTP + sp] = ha | (hb << 16);
        lo[(4 * eq + c) * LDSTP + sp] = la | (lb << 16);
    }
}

// Read a fragment from the padded layout (aligned b128: 80r+16q bytes)
__device__ __forceinline__ bf16x8 read_frag_pad(const unsigned* buf, int row, int q) {
    return *(const bf16x8*)(buf + row * LDSTP + 4 * q);
}

// ---------------------------------------------------------------------------
// Split-bf16 MFMA cores (3 MFMAs per 16x16 tile: AhBh + AhBl + AlBh)
// 128x64 block variants (wave tile 64x32, acc[4][2])
// ---------------------------------------------------------------------------
__device__ __forceinline__ void mfma_ss(const u16* Ah, const u16* Al,
                                        const u16* Bh, const u16* Bl,
                                        f32x4 acc[4][2], int tid) {
    const int lane = tid & 63, w = tid >> 6;
    const int wm = (w & 1) * 64, wn = (w >> 1) * 32;
    const int fr = lane & 15, q = lane >> 4;
    bf16x8 ah[4], al[4];
#pragma unroll
    for (int i = 0; i < 4; ++i) {
        ah[i] = read_frag_sw(Ah, wm + 16 * i + fr, q);
        al[i] = read_frag_sw(Al, wm + 16 * i + fr, q);
    }
#pragma unroll
    for (int j = 0; j < 2; ++j) {
        bf16x8 bh = read_frag_sw(Bh, wn + 16 * j + fr, q);
        bf16x8 bl = read_frag_sw(Bl, wn + 16 * j + fr, q);
#pragma unroll
        for (int i = 0; i < 4; ++i) {
            acc[i][j] = __builtin_amdgcn_mfma_f32_16x16x32_bf16(ah[i], bh, acc[i][j], 0, 0, 0);
            acc[i][j] = __builtin_amdgcn_mfma_f32_16x16x32_bf16(ah[i], bl, acc[i][j], 0, 0, 0);
            acc[i][j] = __builtin_amdgcn_mfma_f32_16x16x32_bf16(al[i], bh, acc[i][j], 0, 0, 0);
        }
    }
}

__device__ __forceinline__ void mfma_sp(const u16* Ah, const u16* Al,
                                        const unsigned* Bh, const unsigned* Bl,
                                        f32x4 acc[4][2], int tid) {
    const int lane = tid & 63, w = tid >> 6;
    const int wm = (w & 1) * 64, wn = (w >> 1) * 32;
    const int fr = lane & 15, q = lane >> 4;
    bf16x8 ah[4], al[4];
#pragma unroll
    for (int i = 0; i < 4; ++i) {
        ah[i] = read_frag_sw(Ah, wm + 16 * i + fr, q);
        al[i] = read_frag_sw(Al, wm + 16 * i + fr, q);
    }
#pragma unroll
    for (int j = 0; j < 2; ++j) {
        bf16x8 bh = read_frag_pad(Bh, wn + 16 * j + fr, q);
        bf16x8 bl = read_frag_pad(Bl, wn + 16 * j + fr, q);
#pragma unroll
        for (int i = 0; i < 4; ++i) {
            acc[i][j] = __builtin_amdgcn_mfma_f32_16x16x32_bf16(ah[i], bh, acc[i][j], 0, 0, 0);
            acc[i][j] = __builtin_amdgcn_mfma_f32_16x16x32_bf16(ah[i], bl, acc[i][j], 0, 0, 0);
            acc[i][j] = __builtin_amdgcn_mfma_f32_16x16x32_bf16(al[i], bh, acc[i][j], 0, 0, 0);
        }
    }
}

// 64x64 block variants (wave tile 32x32, acc[2][2])
__device__ __forceinline__ void mfma_ss64(const u16* Ah, const u16* Al,
                                          const u16* Bh, const u16* Bl,
                                          f32x4 acc[2][2], int tid) {
    const int lane = tid & 63, w = tid >> 6;
    const int wm = (w & 1) * 32, wn = (w >> 1) * 32;
    const int fr = lane & 15, q = lane >> 4;
    bf16x8 ah[2], al[2];
#pragma unroll
    for (int i = 0; i < 2; ++i) {
        ah[i] = read_frag_sw(Ah, wm + 16 * i + fr, q);
        al[i] = read_frag_sw(Al, wm + 16 * i + fr, q);
    }
#pragma unroll
    for (int j = 0; j < 2; ++j) {
        bf16x8 bh = read_frag_sw(Bh, wn + 16 * j + fr, q);
        bf16x8 bl = read_frag_sw(Bl, wn + 16 * j + fr, q);
#pragma unroll
        for (int i = 0; i < 2; ++i) {
            acc[i][j] = __builtin_amdgcn_mfma_f32_16x16x32_bf16(ah[i], bh, acc[i][j], 0, 0, 0);
            acc[i][j] = __builtin_amdgcn_mfma_f32_16x16x32_bf16(ah[i], bl, acc[i][j], 0, 0, 0);
            acc[i][j] = __builtin_amdgcn_mfma_f32_16x16x32_bf16(al[i], bh, acc[i][j], 0, 0, 0);
        }
    }
}

__device__ __forceinline__ void mfma_sp64(const u16* Ah, const u16* Al,
                                          const unsigned* Bh, const unsigned* Bl,
                                          f32x4 acc[2][2], int tid) {
    const int lane = tid & 63, w = tid >> 6;
    const int wm = (w & 1) * 32, wn = (w >> 1) * 32;
    const int fr = lane & 15, q = lane >> 4;
    bf16x8 ah[2], al[2];
#pragma unroll
    for (int i = 0; i < 2; ++i) {
        ah[i] = read_frag_sw(Ah, wm + 16 * i + fr, q);
        al[i] = read_frag_sw(Al, wm + 16 * i + fr, q);
    }
#pragma unroll
    for (int j = 0; j < 2; ++j) {
        bf16x8 bh = read_frag_pad(Bh, wn + 16 * j + fr, q);
        bf16x8 bl = read_frag_pad(Bl, wn + 16 * j + fr, q);
#pragma unroll
        for (int i = 0; i < 2; ++i) {
            acc[i][j] = __builtin_amdgcn_mfma_f32_16x16x32_bf16(ah[i], bh, acc[i][j], 0, 0, 0);
            acc[i][j] = __builtin_amdgcn_mfma_f32_16x16x32_bf16(ah[i], bl, acc[i][j], 0, 0, 0);
            acc[i][j] = __builtin_amdgcn_mfma_f32_16x16x32_bf16(al[i], bh, acc[i][j], 0, 0, 0);
        }
    }
}

// ---------------------------------------------------------------------------
// Convert kernels
// ---------------------------------------------------------------------------
__global__ __launch_bounds__(256) void k_conv(const float* __restrict__ src,
                                              u16* __restrict__ hi, u16* __restrict__ lo) {
    const int i = blockIdx.x * 256 + threadIdx.x;
    float4 v = ((const float4*)src)[i];
    unsigned h0, l0, h1, l1, h2, l2, h3, l3;
    split2(v.x, h0, l0); split2(v.y, h1, l1);
    split2(v.z, h2, l2); split2(v.w, h3, l3);
    ((ushort4*)hi)[i] = make_ushort4((u16)h0, (u16)h1, (u16)h2, (u16)h3);
    ((ushort4*)lo)[i] = make_ushort4((u16)l0, (u16)l1, (u16)l2, (u16)l3);
}

// Wo [1536,512] -> WoT planes [512,1536]
__global__ __launch_bounds__(256) void k_wot(const float* __restrict__ Wo,
                                             u16* __restrict__ thi, u16* __restrict__ tlo) {
    __shared__ float t[64][65];
    const int tid = threadIdx.x;
    const int r0 = blockIdx.x * 64;  // Wo row tile (k)
    const int c0 = blockIdx.y * 64;  // Wo col tile (n)
    const int rr = tid >> 4, cc = tid & 15;
#pragma unroll
    for (int i = 0; i < 4; ++i) {
        float4 v = *(const float4*)(Wo + (size_t)(r0 + rr + 16 * i) * DDIM + c0 + 4 * cc);
        t[rr + 16 * i][4 * cc + 0] = v.x;
        t[rr + 16 * i][4 * cc + 1] = v.y;
        t[rr + 16 * i][4 * cc + 2] = v.z;
        t[rr + 16 * i][4 * cc + 3] = v.w;
    }
    __syncthreads();
#pragma unroll
    for (int i = 0; i < 4; ++i) {
        const int oc = rr + 16 * i;  // WoT row (= Wo col)
        unsigned h0, l0, h1, l1, h2, l2, h3, l3;
        split2(t[4 * cc + 0][oc], h0, l0);
        split2(t[4 * cc + 1][oc], h1, l1);
        split2(t[4 * cc + 2][oc], h2, l2);
        split2(t[4 * cc + 3][oc], h3, l3);
        size_t off = (size_t)(c0 + oc) * (EE + DDIM) + r0 + 4 * cc;
        *(ushort4*)(thi + off) = make_ushort4((u16)h0, (u16)h1, (u16)h2, (u16)h3);
        *(ushort4*)(tlo + off) = make_ushort4((u16)l0, (u16)l1, (u16)l2, (u16)l3);
    }
}

// ---------------------------------------------------------------------------
// K1: decW = dec @ W_attn^T (NT, M=8192, N=1024, K=512) -> hi/lo planes
// ---------------------------------------------------------------------------
__global__ __launch_bounds__(256) void k_decw(const u16* __restrict__ Ahp, const u16* __restrict__ Alp,
                                              const u16* __restrict__ Bhp, const u16* __restrict__ Blp,
                                              u16* __restrict__ Chi, u16* __restrict__ Clo) {
    __shared__ u16 Ah[BM * ROWU], Al[BM * ROWU], Bh[BN * ROWU], Bl[BN * ROWU];
    const int tid = threadIdx.x;
    const int bm = blockIdx.x * BM, bn = blockIdx.y * BN;  // x = m for B-tile L2 reuse
    f32x4 acc[4][2] = {};
    for (int k0 = 0; k0 < DDIM; k0 += BK) {
        __syncthreads();
        stage_glds<BM>(Ah, Ahp + (size_t)bm * DDIM + k0, DDIM, tid);
        stage_glds<BM>(Al, Alp + (size_t)bm * DDIM + k0, DDIM, tid);
        stage_glds<BN>(Bh, Bhp + (size_t)bn * DDIM + k0, DDIM, tid);
        stage_glds<BN>(Bl, Blp + (size_t)bn * DDIM + k0, DDIM, tid);
        __builtin_amdgcn_s_waitcnt(0);
        __syncthreads();
        mfma_ss(Ah, Al, Bh, Bl, acc, tid);
    }
    const int lane = tid & 63, w = tid >> 6;
    const int wm = (w & 1) * 64, wn = (w >> 1) * 32;
    const int fr = lane & 15, q = lane >> 4;
#pragma unroll
    for (int j = 0; j < 2; ++j) {
        const int col = bn + wn + 16 * j + fr;
#pragma unroll
        for (int i = 0; i < 4; ++i)
#pragma unroll
            for (int r = 0; r < 4; ++r) {
                const int row = bm + wm + 16 * i + 4 * q + r;
                unsigned h, l;
                split2(acc[i][j][r], h, l);
                Chi[(size_t)row * EE + col] = (u16)h;
                Clo[(size_t)row * EE + col] = (u16)l;
            }
    }
}

// ---------------------------------------------------------------------------
// K1b: decb[m] = dec[m,:] . b_attn
// ---------------------------------------------------------------------------
__global__ __launch_bounds__(256) void k_decb(const float* __restrict__ dec,
                                              const float* __restrict__ ba,
                                              float* __restrict__ decb) {
    const int row = blockIdx.x * 4 + (threadIdx.x >> 6);
    const int lane = threadIdx.x & 63;
    const float* x = dec + (size_t)row * DDIM;
    float s = 0.f;
#pragma unroll
    for (int i = 0; i < 8; ++i) {
        int idx = lane + i * 64;
        s += x[idx] * ba[idx];
    }
#pragma unroll
    for (int off = 32; off >= 1; off >>= 1) s += __shfl_xor(s, off, 64);
    if (lane == 0) decb[row] = s;
}

// ---------------------------------------------------------------------------
// K2: masked energies (NT batched, M=T=128, N=S, K=E) + bias + mask
// 64x64 block (grid 1024 -> 4 blocks/CU), BK=64 (two 32-subtiles per barrier
// pair, 16 regions). Serial round-0 staging structure.
// ---------------------------------------------------------------------------
__global__ __launch_bounds__(256) void k_energy(const u16* __restrict__ Ahp, const u16* __restrict__ Alp,
                                                const float* __restrict__ enc,
                                                const int* __restrict__ mask,
                                                const float* __restrict__ decb,
                                                float* __restrict__ menerg) {
    const int b = blockIdx.z;
    const int bn = blockIdx.x * BN;
    const int bm = blockIdx.y * BM2;
    __shared__ u16 Ah[2][BM2 * ROWU], Al[2][BM2 * ROWU];
    __shared__ unsigned Bh[2][BN * LDSTP], Bl[2][BN * LDSTP];
    const int tid = threadIdx.x;
    const u16* Abh = Ahp + (size_t)b * TT * EE + (size_t)bm * EE;
    const u16* Abl = Alp + (size_t)b * TT * EE + (size_t)bm * EE;
    const float* Bt = enc + (size_t)b * SS * EE + (size_t)bn * EE;
    f32x4 acc[2][2] = {};
    for (int k0 = 0; k0 < EE; k0 += 2 * BK) {
        __syncthreads();
        stage_glds<BM2>(Ah[0], Abh + k0, EE, tid);
        stage_glds<BM2>(Al[0], Abl + k0, EE, tid);
        stage_glds<BM2>(Ah[1], Abh + k0 + BK, EE, tid);
        stage_glds<BM2>(Al[1], Abl + k0 + BK, EE, tid);
        stage_nt<BN>(Bh[0], Bl[0], Bt + k0, EE, tid);
        stage_nt<BN>(Bh[1], Bl[1], Bt + k0 + BK, EE, tid);
        __builtin_amdgcn_s_waitcnt(0);
        __syncthreads();
        mfma_sp64(Ah[0], Al[0], Bh[0], Bl[0], acc, tid);
        mfma_sp64(Ah[1], Al[1], Bh[1], Bl[1], acc, tid);
    }
    const int lane = tid & 63, w = tid >> 6;
    const int wm = (w & 1) * 32, wn = (w >> 1) * 32;
    const int fr = lane & 15, q = lane >> 4;
    const int* mb = mask + (size_t)b * SS;
    const float* dbp = decb + (size_t)b * TT + bm;
    float* Crow = menerg + (size_t)b * TT * SS + (size_t)bm * SS;
    float db[2][4];
#pragma unroll
    for (int i = 0; i < 2; ++i) {
        float4 d4 = *(const float4*)(dbp + wm + 16 * i + 4 * q);
        db[i][0] = d4.x; db[i][1] = d4.y; db[i][2] = d4.z; db[i][3] = d4.w;
    }
#pragma unroll
    for (int j = 0; j < 2; ++j) {
        const int col = bn + wn + 16 * j + fr;
        const int mk = mb[col];
#pragma unroll
        for (int i = 0; i < 2; ++i)
#pragma unroll
            for (int r = 0; r < 4; ++r) {
                const int row = wm + 16 * i + 4 * q + r;
                Crow[(size_t)row * SS + col] = mk ? acc[i][j][r] + db[i][r] : NEG_INF_F;
            }
    }
}

// ---------------------------------------------------------------------------
// K3: softmax over S=512 -> attn fp32 (output) + attn hi/lo planes
// ---------------------------------------------------------------------------
__global__ __launch_bounds__(128) void k_softmax(const float* __restrict__ me,
                                                 float* __restrict__ attn,
                                                 u16* __restrict__ ahi,
                                                 u16* __restrict__ alo) {
    const int row = blockIdx.x;
    const int tid = threadIdx.x;
    const float4 v = ((const float4*)(me + (size_t)row * SS))[tid];
    float m = fmaxf(fmaxf(v.x, v.y), fmaxf(v.z, v.w));
#pragma unroll
    for (int off = 32; off >= 1; off >>= 1) m = fmaxf(m, __shfl_xor(m, off, 64));
    __shared__ float redm[2];
    __shared__ float reds[2];
    const int wv = tid >> 6, lane = tid & 63;
    if (lane == 0) redm[wv] = m;
    __syncthreads();
    m = fmaxf(redm[0], redm[1]);
    float e0 = __expf(v.x - m), e1 = __expf(v.y - m);
    float e2 = __expf(v.z - m), e3 = __expf(v.w - m);
    float s = (e0 + e1) + (e2 + e3);
#pragma unroll
    for (int off = 32; off >= 1; off >>= 1) s += __shfl_xor(s, off, 64);
    if (lane == 0) reds[wv] = s;
    __syncthreads();
    s = reds[0] + reds[1];
    const float inv = 1.0f / s;
    float o0 = e0 * inv, o1 = e1 * inv, o2 = e2 * inv, o3 = e3 * inv;
    ((float4*)(attn + (size_t)row * SS))[tid] = make_float4(o0, o1, o2, o3);
    unsigned h0, l0, h1, l1, h2, l2, h3, l3;
    split2(o0, h0, l0); split2(o1, h1, l1); split2(o2, h2, l2); split2(o3, h3, l3);
    ((ushort4*)(ahi + (size_t)row * SS))[tid] = make_ushort4((u16)h0, (u16)h1, (u16)h2, (u16)h3);
    ((ushort4*)(alo + (size_t)row * SS))[tid] = make_ushort4((u16)l0, (u16)l1, (u16)l2, (u16)l3);
}

// ---------------------------------------------------------------------------
// K4: wc = attn @ enc (NN batched, M=T, N=E, K=S) -> wc hi/lo planes
// ---------------------------------------------------------------------------
__global__ __launch_bounds__(256) void k_ctx(const u16* __restrict__ Ahp, const u16* __restrict__ Alp,
                                             const float* __restrict__ enc,
                                             u16* __restrict__ Chi, u16* __restrict__ Clo) {
    const int b = blockIdx.z;
    const int bn = blockIdx.x * BN;  // over E
    __shared__ u16 Ah[BM * ROWU], Al[BM * ROWU];
    __shared__ unsigned Bh[BN * LDSTP], Bl[BN * LDSTP];
    const int tid = threadIdx.x;
    const u16* Abh = Ahp + (size_t)b * TT * SS;
    const u16* Abl = Alp + (size_t)b * TT * SS;
    const float* Bm = enc + (size_t)b * SS * EE + bn;
    f32x4 acc[4][2] = {};
    for (int k0 = 0; k0 < SS; k0 += BK) {
        __syncthreads();
        stage_glds<BM>(Ah, Abh + k0, SS, tid);
        stage_glds<BM>(Al, Abl + k0, SS, tid);
        stage_tr(Bh, Bl, Bm + (size_t)k0 * EE, EE, tid);
        __builtin_amdgcn_s_waitcnt(0);
        __syncthreads();
        mfma_sp(Ah, Al, Bh, Bl, acc, tid);
    }
    const int lane = tid & 63, w = tid >> 6;
    const int wm = (w & 1) * 64, wn = (w >> 1) * 32;
    const int fr = lane & 15, q = lane >> 4;
    u16* Ch = Chi + (size_t)b * TT * EE;
    u16* Cl = Clo + (size_t)b * TT * EE;
#pragma unroll
    for (int j = 0; j < 2; ++j) {
        const int col = bn + wn + 16 * j + fr;
#pragma unroll
        for (int i = 0; i < 4; ++i)
#pragma unroll
            for (int r = 0; r < 4; ++r) {
                const int row = wm + 16 * i + 4 * q + r;
                unsigned h, l;
                split2(acc[i][j][r], h, l);
                Ch[(size_t)row * EE + col] = (u16)h;
                Cl[(size_t)row * EE + col] = (u16)l;
            }
    }
}

// ---------------------------------------------------------------------------
// K5: h_tilde = tanh([wc | dec] @ W_out) via WoT planes (NT, M=8192, N=512, K=1536)
// 64x64 block (grid 1024 -> 4 blocks/CU).
// ---------------------------------------------------------------------------
__global__ __launch_bounds__(256) void k_out(const u16* __restrict__ wch, const u16* __restrict__ wcl,
                                             const u16* __restrict__ dech, const u16* __restrict__ decl,
                                             const u16* __restrict__ woth, const u16* __restrict__ wotl,
                                             float* __restrict__ ht) {
    __shared__ u16 Ah[BM2 * ROWU], Al[BM2 * ROWU], Bh[BN * ROWU], Bl[BN * ROWU];
    const int tid = threadIdx.x;
    const int bm = blockIdx.x * BM2, bn = blockIdx.y * BN;  // x = m for B-tile reuse
    f32x4 acc[2][2] = {};
    for (int k0 = 0; k0 < EE + DDIM; k0 += BK) {
        const u16 *ah, *al;
        int ld;
        if (k0 < EE) {
            ah = wch + (size_t)bm * EE + k0;
            al = wcl + (size_t)bm * EE + k0;
            ld = EE;
        } else {
            ah = dech + (size_t)bm * DDIM + (k0 - EE);
            al = decl + (size_t)bm * DDIM + (k0 - EE);
            ld = DDIM;
        }
        __syncthreads();
        stage_glds<BM2>(Ah, ah, ld, tid);
        stage_glds<BM2>(Al, al, ld, tid);
        stage_glds<BN>(Bh, woth + (size_t)bn * (EE + DDIM) + k0, EE + DDIM, tid);
        stage_glds<BN>(Bl, wotl + (size_t)bn * (EE + DDIM) + k0, EE + DDIM, tid);
        __builtin_amdgcn_s_waitcnt(0);
        __syncthreads();
        mfma_ss64(Ah, Al, Bh, Bl, acc, tid);
    }
    const int lane = tid & 63, w = tid >> 6;
    const int wm = (w & 1) * 32, wn = (w >> 1) * 32;
    const int fr = lane & 15, q = lane >> 4;
#pragma unroll
    for (int j = 0; j < 2; ++j) {
        const int col = bn + wn + 16 * j + fr;
#pragma unroll
        for (int i = 0; i < 2; ++i)
#pragma unroll
            for (int r = 0; r < 4; ++r) {
                const int row = bm + wm + 16 * i + 4 * q + r;
                ht[(size_t)row * DDIM + col] = tanhf(acc[i][j][r]);
            }
    }
}

// ---------------------------------------------------------------------------
extern "C" void kernel_launch(void* const* d_in, const int* in_sizes, int n_in,
                              void* d_out, int out_size, void* d_ws, size_t ws_size,
                              hipStream_t stream) {
    (void)in_sizes; (void)n_in; (void)out_size; (void)ws_size;
    const float* dec = (const float*)d_in[0];
    const float* enc = (const float*)d_in[1];
    const int* mask = (const int*)d_in[2];
    const float* Wa = (const float*)d_in[3];
    const float* ba = (const float*)d_in[4];
    const float* Wo = (const float*)d_in[5];

    float* h_tilde = (float*)d_out;
    float* attn = h_tilde + (size_t)BB * TT * DDIM;
    float* menerg = attn + (size_t)BB * TT * SS;

    // Workspace layout (bytes), total ~72.4 MB
    char* ws = (char*)d_ws;
    u16* decW_hi = (u16*)(ws);                       // 8192x1024 u16 = 16.78 MB
    u16* decW_lo = (u16*)(ws + 16777216);
    u16* dec_hi  = (u16*)(ws + 33554432);            // 8192x512
    u16* dec_lo  = (u16*)(ws + 41943040);
    u16* attn_hi = (u16*)(ws + 50331648);            // 8192x512
    u16* attn_lo = (u16*)(ws + 58720256);
    u16* wa_hi   = (u16*)(ws + 67108864);            // 1024x512
    u16* wa_lo   = (u16*)(ws + 68157440);
    u16* wot_hi  = (u16*)(ws + 69206016);            // 512x1536
    u16* wot_lo  = (u16*)(ws + 70778880);
    float* decb  = (float*)(ws + 72351744);          // 8192 f32
    // wc planes alias decW planes (decW dead after k_energy)
    u16* wc_hi = decW_hi;
    u16* wc_lo = decW_lo;

    k_conv<<<(BB * TT * DDIM) / 4 / 256, 256, 0, stream>>>(dec, dec_hi, dec_lo);
    k_conv<<<(EE * DDIM) / 4 / 256, 256, 0, stream>>>(Wa, wa_hi, wa_lo);
    k_wot<<<dim3((EE + DDIM) / 64, DDIM / 64), 256, 0, stream>>>(Wo, wot_hi, wot_lo);
    k_decb<<<(BB * TT) / 4, 256, 0, stream>>>(dec, ba, decb);
    k_decw<<<dim3((BB * TT) / BM, EE / BN), 256, 0, stream>>>(dec_hi, dec_lo, wa_hi, wa_lo,
                                                              decW_hi, decW_lo);
    k_energy<<<dim3(SS / BN, TT / BM2, BB), 256, 0, stream>>>(decW_hi, decW_lo, enc, mask, decb,
                                                              menerg);
    k_softmax<<<BB * TT, 128, 0, stream>>>(menerg, attn, attn_hi, attn_lo);
    k_ctx<<<dim3(EE / BN, 1, BB), 256, 0, stream>>>(attn_hi, attn_lo, enc, wc_hi, wc_lo);
    k_out<<<dim3((BB * TT) / BM2, DDIM / BN), 256, 0, stream>>>(wc_hi, wc_lo, dec_hi, dec_lo,
                                                                wot_hi, wot_lo, h_tilde);
}

// Round 3
// 383.124 us; speedup vs baseline: 1.1761x; 1.0785x over previous
//
#include <hip/hip_runtime.h>
#include <cmath>

// Problem constants
#define BB 64
#define TT 128
#define SS 512
#define EE 1024
#define DDIM 512
#define NEG_INF_F (-1.0e10f)

// MFMA tiling
#define BM 128
#define BM2 64   // half-height block for grid-limited kernels (wave tile 32x32)
#define BN 64
#define BK 32
#define LDSTP 20   // padded layout row stride (dwords): 80 B rows -> b128-aligned, 2-way banks (free)
#define ROWU 32    // swizzled plane layout row stride in u16 (64 B/row)

typedef unsigned short u16;
typedef __attribute__((ext_vector_type(8))) short bf16x8;
typedef __attribute__((ext_vector_type(4))) float f32x4;

// ---------------------------------------------------------------------------
// fp32 -> bf16 split (hi = rne(f), lo = rne(f - hi)); ~2^-18 rel error
// ---------------------------------------------------------------------------
__device__ __forceinline__ unsigned bf16_rne(float f) {
    unsigned u = __float_as_uint(f);
    return (u + 0x7fffu + ((u >> 16) & 1u)) >> 16;
}
__device__ __forceinline__ void split2(float f, unsigned& h, unsigned& l) {
    h = bf16_rne(f);
    float fh = __uint_as_float(h << 16);
    l = bf16_rne(f - fh);
}

// ---------------------------------------------------------------------------
// glds staging of a bf16 plane tile: ROWS rows x 32 bf16 (64 B/row), with the
// quad-swizzle chunk(q)->slot q^((r>>1)&3). Lane-linear LDS writes (16 B/lane).
// ---------------------------------------------------------------------------
template <int ROWS>
__device__ __forceinline__ void stage_glds(u16* lds, const u16* __restrict__ src,
                                           int ld, int tid) {
    const int w = tid >> 6, lane = tid & 63;
    const int rl = lane >> 2, p = lane & 3;
#pragma unroll
    for (int i = 0; i < ROWS / 64; ++i) {
        const int r0 = (w + 4 * i) * 16;
        const int r = r0 + rl;
        const int q = p ^ ((r >> 1) & 3);
        const u16* g = src + (size_t)r * ld + 8 * q;
        __builtin_amdgcn_global_load_lds(
            (const __attribute__((address_space(1))) unsigned*)g,
            (__attribute__((address_space(3))) unsigned*)(lds + r0 * ROWU),
            16, 0, 0);
    }
}

// Read a 16x16x32 fragment from the swizzled plane layout (one ds_read_b128)
__device__ __forceinline__ bf16x8 read_frag_sw(const u16* buf, int row, int q) {
    const int c = q ^ ((row >> 1) & 3);
    return *(const bf16x8*)(buf + row * ROWU + 8 * c);
}

// ---------------------------------------------------------------------------
// VALU staging of an NT fp32 operand (rows x BK, k contiguous) into padded
// hi/lo LDS (u32 = bf16 pair (2k,2k+1)). Used for enc in k_energy.
// ---------------------------------------------------------------------------
template <int ROWS>
__device__ __forceinline__ void stage_nt(unsigned* hi, unsigned* lo,
                                         const float* __restrict__ src, int ld, int tid) {
#pragma unroll
    for (int i = 0; i < ROWS / 32; ++i) {
        int s = tid + 256 * i;
        int r = s >> 3, kq = s & 7;
        float4 v = *(const float4*)(src + (size_t)r * ld + 4 * kq);
        unsigned h0, l0, h1, l1, h2, l2, h3, l3;
        split2(v.x, h0, l0); split2(v.y, h1, l1);
        split2(v.z, h2, l2); split2(v.w, h3, l3);
        *(uint2*)&hi[r * LDSTP + 2 * kq] = make_uint2(h0 | (h1 << 16), h2 | (h3 << 16));
        *(uint2*)&lo[r * LDSTP + 2 * kq] = make_uint2(l0 | (l1 << 16), l2 | (l3 << 16));
    }
}

// ---------------------------------------------------------------------------
// Single-plane VALU staging of a transposed fp32 B tile (k_ctx, 32 k-rows):
// global [32 k][BN n] -> padded LDS rows = n, bf16 rne only (no lo plane).
// ---------------------------------------------------------------------------
__device__ __forceinline__ void stage_tr1(unsigned* hi, const float* __restrict__ src,
                                          int ld, int tid) {
    int eq = tid & 15;   // n quad
    int sp = tid >> 4;   // k pair
    const float* p = src + (size_t)(2 * sp) * ld + 4 * eq;
    float4 va = *(const float4*)p;
    float4 vb = *(const float4*)(p + ld);
    float av[4] = {va.x, va.y, va.z, va.w};
    float bv[4] = {vb.x, vb.y, vb.z, vb.w};
#pragma unroll
    for (int c = 0; c < 4; ++c) {
        hi[(4 * eq + c) * LDSTP + sp] = bf16_rne(av[c]) | (bf16_rne(bv[c]) << 16);
    }
}

// Read a fragment from the padded layout (aligned b128: 80r+16q bytes)
__device__ __forceinline__ bf16x8 read_frag_pad(const unsigned* buf, int row, int q) {
    return *(const bf16x8*)(buf + row * LDSTP + 4 * q);
}

// ---------------------------------------------------------------------------
// Split-bf16 MFMA cores (3 MFMAs per 16x16 tile: AhBh + AhBl + AlBh)
// ---------------------------------------------------------------------------
__device__ __forceinline__ void mfma_ss(const u16* Ah, const u16* Al,
                                        const u16* Bh, const u16* Bl,
                                        f32x4 acc[4][2], int tid) {
    const int lane = tid & 63, w = tid >> 6;
    const int wm = (w & 1) * 64, wn = (w >> 1) * 32;
    const int fr = lane & 15, q = lane >> 4;
    bf16x8 ah[4], al[4];
#pragma unroll
    for (int i = 0; i < 4; ++i) {
        ah[i] = read_frag_sw(Ah, wm + 16 * i + fr, q);
        al[i] = read_frag_sw(Al, wm + 16 * i + fr, q);
    }
#pragma unroll
    for (int j = 0; j < 2; ++j) {
        bf16x8 bh = read_frag_sw(Bh, wn + 16 * j + fr, q);
        bf16x8 bl = read_frag_sw(Bl, wn + 16 * j + fr, q);
#pragma unroll
        for (int i = 0; i < 4; ++i) {
            acc[i][j] = __builtin_amdgcn_mfma_f32_16x16x32_bf16(ah[i], bh, acc[i][j], 0, 0, 0);
            acc[i][j] = __builtin_amdgcn_mfma_f32_16x16x32_bf16(ah[i], bl, acc[i][j], 0, 0, 0);
            acc[i][j] = __builtin_amdgcn_mfma_f32_16x16x32_bf16(al[i], bh, acc[i][j], 0, 0, 0);
        }
    }
}

// 64x64 block, split-split (k_decw)
__device__ __forceinline__ void mfma_ss64(const u16* Ah, const u16* Al,
                                          const u16* Bh, const u16* Bl,
                                          f32x4 acc[2][2], int tid) {
    const int lane = tid & 63, w = tid >> 6;
    const int wm = (w & 1) * 32, wn = (w >> 1) * 32;
    const int fr = lane & 15, q = lane >> 4;
    bf16x8 ah[2], al[2];
#pragma unroll
    for (int i = 0; i < 2; ++i) {
        ah[i] = read_frag_sw(Ah, wm + 16 * i + fr, q);
        al[i] = read_frag_sw(Al, wm + 16 * i + fr, q);
    }
#pragma unroll
    for (int j = 0; j < 2; ++j) {
        bf16x8 bh = read_frag_sw(Bh, wn + 16 * j + fr, q);
        bf16x8 bl = read_frag_sw(Bl, wn + 16 * j + fr, q);
#pragma unroll
        for (int i = 0; i < 2; ++i) {
            acc[i][j] = __builtin_amdgcn_mfma_f32_16x16x32_bf16(ah[i], bh, acc[i][j], 0, 0, 0);
            acc[i][j] = __builtin_amdgcn_mfma_f32_16x16x32_bf16(ah[i], bl, acc[i][j], 0, 0, 0);
            acc[i][j] = __builtin_amdgcn_mfma_f32_16x16x32_bf16(al[i], bh, acc[i][j], 0, 0, 0);
        }
    }
}

// 64x64 block, split-A / padded-split-B (k_energy)
__device__ __forceinline__ void mfma_sp64(const u16* Ah, const u16* Al,
                                          const unsigned* Bh, const unsigned* Bl,
                                          f32x4 acc[2][2], int tid) {
    const int lane = tid & 63, w = tid >> 6;
    const int wm = (w & 1) * 32, wn = (w >> 1) * 32;
    const int fr = lane & 15, q = lane >> 4;
    bf16x8 ah[2], al[2];
#pragma unroll
    for (int i = 0; i < 2; ++i) {
        ah[i] = read_frag_sw(Ah, wm + 16 * i + fr, q);
        al[i] = read_frag_sw(Al, wm + 16 * i + fr, q);
    }
#pragma unroll
    for (int j = 0; j < 2; ++j) {
        bf16x8 bh = read_frag_pad(Bh, wn + 16 * j + fr, q);
        bf16x8 bl = read_frag_pad(Bl, wn + 16 * j + fr, q);
#pragma unroll
        for (int i = 0; i < 2; ++i) {
            acc[i][j] = __builtin_amdgcn_mfma_f32_16x16x32_bf16(ah[i], bh, acc[i][j], 0, 0, 0);
            acc[i][j] = __builtin_amdgcn_mfma_f32_16x16x32_bf16(ah[i], bl, acc[i][j], 0, 0, 0);
            acc[i][j] = __builtin_amdgcn_mfma_f32_16x16x32_bf16(al[i], bh, acc[i][j], 0, 0, 0);
        }
    }
}

// 128x64 block, single-bf16 A (sw plane) x single-bf16 B (padded) — k_ctx
__device__ __forceinline__ void mfma_sp1(const u16* Ah, const unsigned* Bh,
                                         f32x4 acc[4][2], int tid) {
    const int lane = tid & 63, w = tid >> 6;
    const int wm = (w & 1) * 64, wn = (w >> 1) * 32;
    const int fr = lane & 15, q = lane >> 4;
    bf16x8 ah[4];
#pragma unroll
    for (int i = 0; i < 4; ++i) ah[i] = read_frag_sw(Ah, wm + 16 * i + fr, q);
#pragma unroll
    for (int j = 0; j < 2; ++j) {
        bf16x8 bh = read_frag_pad(Bh, wn + 16 * j + fr, q);
#pragma unroll
        for (int i = 0; i < 4; ++i)
            acc[i][j] = __builtin_amdgcn_mfma_f32_16x16x32_bf16(ah[i], bh, acc[i][j], 0, 0, 0);
    }
}

// ---------------------------------------------------------------------------
// Convert kernels
// ---------------------------------------------------------------------------
__global__ __launch_bounds__(256) void k_conv(const float* __restrict__ src,
                                              u16* __restrict__ hi, u16* __restrict__ lo) {
    const int i = blockIdx.x * 256 + threadIdx.x;
    float4 v = ((const float4*)src)[i];
    unsigned h0, l0, h1, l1, h2, l2, h3, l3;
    split2(v.x, h0, l0); split2(v.y, h1, l1);
    split2(v.z, h2, l2); split2(v.w, h3, l3);
    ((ushort4*)hi)[i] = make_ushort4((u16)h0, (u16)h1, (u16)h2, (u16)h3);
    ((ushort4*)lo)[i] = make_ushort4((u16)l0, (u16)l1, (u16)l2, (u16)l3);
}

// Wo [1536,512] -> WoT planes [512,1536]
__global__ __launch_bounds__(256) void k_wot(const float* __restrict__ Wo,
                                             u16* __restrict__ thi, u16* __restrict__ tlo) {
    __shared__ float t[64][65];
    const int tid = threadIdx.x;
    const int r0 = blockIdx.x * 64;  // Wo row tile (k)
    const int c0 = blockIdx.y * 64;  // Wo col tile (n)
    const int rr = tid >> 4, cc = tid & 15;
#pragma unroll
    for (int i = 0; i < 4; ++i) {
        float4 v = *(const float4*)(Wo + (size_t)(r0 + rr + 16 * i) * DDIM + c0 + 4 * cc);
        t[rr + 16 * i][4 * cc + 0] = v.x;
        t[rr + 16 * i][4 * cc + 1] = v.y;
        t[rr + 16 * i][4 * cc + 2] = v.z;
        t[rr + 16 * i][4 * cc + 3] = v.w;
    }
    __syncthreads();
#pragma unroll
    for (int i = 0; i < 4; ++i) {
        const int oc = rr + 16 * i;  // WoT row (= Wo col)
        unsigned h0, l0, h1, l1, h2, l2, h3, l3;
        split2(t[4 * cc + 0][oc], h0, l0);
        split2(t[4 * cc + 1][oc], h1, l1);
        split2(t[4 * cc + 2][oc], h2, l2);
        split2(t[4 * cc + 3][oc], h3, l3);
        size_t off = (size_t)(c0 + oc) * (EE + DDIM) + r0 + 4 * cc;
        *(ushort4*)(thi + off) = make_ushort4((u16)h0, (u16)h1, (u16)h2, (u16)h3);
        *(ushort4*)(tlo + off) = make_ushort4((u16)l0, (u16)l1, (u16)l2, (u16)l3);
    }
}

// ---------------------------------------------------------------------------
// K1: decW = dec @ W_attn^T (NT, M=8192, N=1024, K=512) -> hi/lo planes
// 64x64 block (grid 2048 -> 5 blk/CU by LDS), BK=64 as 2x32 subtiles.
// ---------------------------------------------------------------------------
__global__ __launch_bounds__(256) void k_decw(const u16* __restrict__ Ahp, const u16* __restrict__ Alp,
                                              const u16* __restrict__ Bhp, const u16* __restrict__ Blp,
                                              u16* __restrict__ Chi, u16* __restrict__ Clo) {
    __shared__ u16 Ah[2][BM2 * ROWU], Al[2][BM2 * ROWU], Bh[2][BN * ROWU], Bl[2][BN * ROWU];
    const int tid = threadIdx.x;
    const int bm = blockIdx.x * BM2, bn = blockIdx.y * BN;  // x = m for B-tile L2 reuse
    f32x4 acc[2][2] = {};
    for (int k0 = 0; k0 < DDIM; k0 += 2 * BK) {
        __syncthreads();
        stage_glds<BM2>(Ah[0], Ahp + (size_t)bm * DDIM + k0, DDIM, tid);
        stage_glds<BM2>(Al[0], Alp + (size_t)bm * DDIM + k0, DDIM, tid);
        stage_glds<BM2>(Ah[1], Ahp + (size_t)bm * DDIM + k0 + BK, DDIM, tid);
        stage_glds<BM2>(Al[1], Alp + (size_t)bm * DDIM + k0 + BK, DDIM, tid);
        stage_glds<BN>(Bh[0], Bhp + (size_t)bn * DDIM + k0, DDIM, tid);
        stage_glds<BN>(Bl[0], Blp + (size_t)bn * DDIM + k0, DDIM, tid);
        stage_glds<BN>(Bh[1], Bhp + (size_t)bn * DDIM + k0 + BK, DDIM, tid);
        stage_glds<BN>(Bl[1], Blp + (size_t)bn * DDIM + k0 + BK, DDIM, tid);
        __builtin_amdgcn_s_waitcnt(0);
        __syncthreads();
        mfma_ss64(Ah[0], Al[0], Bh[0], Bl[0], acc, tid);
        mfma_ss64(Ah[1], Al[1], Bh[1], Bl[1], acc, tid);
    }
    const int lane = tid & 63, w = tid >> 6;
    const int wm = (w & 1) * 32, wn = (w >> 1) * 32;
    const int fr = lane & 15, q = lane >> 4;
#pragma unroll
    for (int j = 0; j < 2; ++j) {
        const int col = bn + wn + 16 * j + fr;
#pragma unroll
        for (int i = 0; i < 2; ++i)
#pragma unroll
            for (int r = 0; r < 4; ++r) {
                const int row = bm + wm + 16 * i + 4 * q + r;
                unsigned h, l;
                split2(acc[i][j][r], h, l);
                Chi[(size_t)row * EE + col] = (u16)h;
                Clo[(size_t)row * EE + col] = (u16)l;
            }
    }
}

// ---------------------------------------------------------------------------
// K1b: decb[m] = dec[m,:] . b_attn
// ---------------------------------------------------------------------------
__global__ __launch_bounds__(256) void k_decb(const float* __restrict__ dec,
                                              const float* __restrict__ ba,
                                              float* __restrict__ decb) {
    const int row = blockIdx.x * 4 + (threadIdx.x >> 6);
    const int lane = threadIdx.x & 63;
    const float* x = dec + (size_t)row * DDIM;
    float s = 0.f;
#pragma unroll
    for (int i = 0; i < 8; ++i) {
        int idx = lane + i * 64;
        s += x[idx] * ba[idx];
    }
#pragma unroll
    for (int off = 32; off >= 1; off >>= 1) s += __shfl_xor(s, off, 64);
    if (lane == 0) decb[row] = s;
}

// ---------------------------------------------------------------------------
// K2: masked energies (NT batched, M=T=128, N=S, K=E) + bias + mask
// 64x64 block (grid 1024 -> 4 blocks/CU), BK=64 (two 32-subtiles per barrier
// pair, 16 regions). Best-measured round-2 form, unchanged.
// ---------------------------------------------------------------------------
__global__ __launch_bounds__(256) void k_energy(const u16* __restrict__ Ahp, const u16* __restrict__ Alp,
                                                const float* __restrict__ enc,
                                                const int* __restrict__ mask,
                                                const float* __restrict__ decb,
                                                float* __restrict__ menerg) {
    const int b = blockIdx.z;
    const int bn = blockIdx.x * BN;
    const int bm = blockIdx.y * BM2;
    __shared__ u16 Ah[2][BM2 * ROWU], Al[2][BM2 * ROWU];
    __shared__ unsigned Bh[2][BN * LDSTP], Bl[2][BN * LDSTP];
    const int tid = threadIdx.x;
    const u16* Abh = Ahp + (size_t)b * TT * EE + (size_t)bm * EE;
    const u16* Abl = Alp + (size_t)b * TT * EE + (size_t)bm * EE;
    const float* Bt = enc + (size_t)b * SS * EE + (size_t)bn * EE;
    f32x4 acc[2][2] = {};
    for (int k0 = 0; k0 < EE; k0 += 2 * BK) {
        __syncthreads();
        stage_glds<BM2>(Ah[0], Abh + k0, EE, tid);
        stage_glds<BM2>(Al[0], Abl + k0, EE, tid);
        stage_glds<BM2>(Ah[1], Abh + k0 + BK, EE, tid);
        stage_glds<BM2>(Al[1], Abl + k0 + BK, EE, tid);
        stage_nt<BN>(Bh[0], Bl[0], Bt + k0, EE, tid);
        stage_nt<BN>(Bh[1], Bl[1], Bt + k0 + BK, EE, tid);
        __builtin_amdgcn_s_waitcnt(0);
        __syncthreads();
        mfma_sp64(Ah[0], Al[0], Bh[0], Bl[0], acc, tid);
        mfma_sp64(Ah[1], Al[1], Bh[1], Bl[1], acc, tid);
    }
    const int lane = tid & 63, w = tid >> 6;
    const int wm = (w & 1) * 32, wn = (w >> 1) * 32;
    const int fr = lane & 15, q = lane >> 4;
    const int* mb = mask + (size_t)b * SS;
    const float* dbp = decb + (size_t)b * TT + bm;
    float* Crow = menerg + (size_t)b * TT * SS + (size_t)bm * SS;
    float db[2][4];
#pragma unroll
    for (int i = 0; i < 2; ++i) {
        float4 d4 = *(const float4*)(dbp + wm + 16 * i + 4 * q);
        db[i][0] = d4.x; db[i][1] = d4.y; db[i][2] = d4.z; db[i][3] = d4.w;
    }
#pragma unroll
    for (int j = 0; j < 2; ++j) {
        const int col = bn + wn + 16 * j + fr;
        const int mk = mb[col];
#pragma unroll
        for (int i = 0; i < 2; ++i)
#pragma unroll
            for (int r = 0; r < 4; ++r) {
                const int row = wm + 16 * i + 4 * q + r;
                Crow[(size_t)row * SS + col] = mk ? acc[i][j][r] + db[i][r] : NEG_INF_F;
            }
    }
}

// ---------------------------------------------------------------------------
// K3: softmax over S=512 -> attn fp32 (output) + attn hi plane (bf16 rne)
// ---------------------------------------------------------------------------
__global__ __launch_bounds__(128) void k_softmax(const float* __restrict__ me,
                                                 float* __restrict__ attn,
                                                 u16* __restrict__ ahi) {
    const int row = blockIdx.x;
    const int tid = threadIdx.x;
    const float4 v = ((const float4*)(me + (size_t)row * SS))[tid];
    float m = fmaxf(fmaxf(v.x, v.y), fmaxf(v.z, v.w));
#pragma unroll
    for (int off = 32; off >= 1; off >>= 1) m = fmaxf(m, __shfl_xor(m, off, 64));
    __shared__ float redm[2];
    __shared__ float reds[2];
    const int wv = tid >> 6, lane = tid & 63;
    if (lane == 0) redm[wv] = m;
    __syncthreads();
    m = fmaxf(redm[0], redm[1]);
    float e0 = __expf(v.x - m), e1 = __expf(v.y - m);
    float e2 = __expf(v.z - m), e3 = __expf(v.w - m);
    float s = (e0 + e1) + (e2 + e3);
#pragma unroll
    for (int off = 32; off >= 1; off >>= 1) s += __shfl_xor(s, off, 64);
    if (lane == 0) reds[wv] = s;
    __syncthreads();
    s = reds[0] + reds[1];
    const float inv = 1.0f / s;
    float o0 = e0 * inv, o1 = e1 * inv, o2 = e2 * inv, o3 = e3 * inv;
    ((float4*)(attn + (size_t)row * SS))[tid] = make_float4(o0, o1, o2, o3);
    ((ushort4*)(ahi + (size_t)row * SS))[tid] =
        make_ushort4((u16)bf16_rne(o0), (u16)bf16_rne(o1),
                     (u16)bf16_rne(o2), (u16)bf16_rne(o3));
}

// ---------------------------------------------------------------------------
// K4: wc = attn @ enc (NN batched, M=T, N=E, K=S) -> wc hi/lo planes
// SINGLE-bf16 operands (attn in [0,1], enc ~N(0,1): wc abs err ~3e-3, only
// feeds h_tilde via tanh — negligible). 1 MFMA per tile, BK=64 subtiles.
// ---------------------------------------------------------------------------
__global__ __launch_bounds__(256) void k_ctx(const u16* __restrict__ Ahp,
                                             const float* __restrict__ enc,
                                             u16* __restrict__ Chi, u16* __restrict__ Clo) {
    const int b = blockIdx.z;
    const int bn = blockIdx.x * BN;  // over E
    __shared__ u16 Ah[2][BM * ROWU];
    __shared__ unsigned Bh[2][BN * LDSTP];
    const int tid = threadIdx.x;
    const u16* Abh = Ahp + (size_t)b * TT * SS;
    const float* Bm = enc + (size_t)b * SS * EE + bn;
    f32x4 acc[4][2] = {};
    for (int k0 = 0; k0 < SS; k0 += 2 * BK) {
        __syncthreads();
        stage_glds<BM>(Ah[0], Abh + k0, SS, tid);
        stage_glds<BM>(Ah[1], Abh + k0 + BK, SS, tid);
        stage_tr1(Bh[0], Bm + (size_t)k0 * EE, EE, tid);
        stage_tr1(Bh[1], Bm + (size_t)(k0 + BK) * EE, EE, tid);
        __builtin_amdgcn_s_waitcnt(0);
        __syncthreads();
        mfma_sp1(Ah[0], Bh[0], acc, tid);
        mfma_sp1(Ah[1], Bh[1], acc, tid);
    }
    const int lane = tid & 63, w = tid >> 6;
    const int wm = (w & 1) * 64, wn = (w >> 1) * 32;
    const int fr = lane & 15, q = lane >> 4;
    u16* Ch = Chi + (size_t)b * TT * EE;
    u16* Cl = Clo + (size_t)b * TT * EE;
#pragma unroll
    for (int j = 0; j < 2; ++j) {
        const int col = bn + wn + 16 * j + fr;
#pragma unroll
        for (int i = 0; i < 4; ++i)
#pragma unroll
            for (int r = 0; r < 4; ++r) {
                const int row = wm + 16 * i + 4 * q + r;
                unsigned h, l;
                split2(acc[i][j][r], h, l);
                Ch[(size_t)row * EE + col] = (u16)h;
                Cl[(size_t)row * EE + col] = (u16)l;
            }
    }
}

// ---------------------------------------------------------------------------
// K5: h_tilde = tanh([wc | dec] @ W_out) via WoT planes (NT, M=8192, N=512, K=1536)
// 128x64 block (round-0 shape), BK=64 as 2x32 subtiles (24 barrier regions).
// ---------------------------------------------------------------------------
__global__ __launch_bounds__(256) void k_out(const u16* __restrict__ wch, const u16* __restrict__ wcl,
                                             const u16* __restrict__ dech, const u16* __restrict__ decl,
                                             const u16* __restrict__ woth, const u16* __restrict__ wotl,
                                             float* __restrict__ ht) {
    __shared__ u16 Ah[2][BM * ROWU], Al[2][BM * ROWU], Bh[2][BN * ROWU], Bl[2][BN * ROWU];
    const int tid = threadIdx.x;
    const int bm = blockIdx.x * BM, bn = blockIdx.y * BN;  // x = m for B-tile reuse
    const int KTOT = EE + DDIM;
    f32x4 acc[4][2] = {};
    for (int k0 = 0; k0 < KTOT; k0 += 2 * BK) {
        __syncthreads();
#pragma unroll
        for (int s = 0; s < 2; ++s) {
            const int kk = k0 + BK * s;
            const u16 *ah, *al;
            int ld;
            if (kk < EE) {
                ah = wch + (size_t)bm * EE + kk;
                al = wcl + (size_t)bm * EE + kk;
                ld = EE;
            } else {
                ah = dech + (size_t)bm * DDIM + (kk - EE);
                al = decl + (size_t)bm * DDIM + (kk - EE);
                ld = DDIM;
            }
            stage_glds<BM>(Ah[s], ah, ld, tid);
            stage_glds<BM>(Al[s], al, ld, tid);
            stage_glds<BN>(Bh[s], woth + (size_t)bn * KTOT + kk, KTOT, tid);
            stage_glds<BN>(Bl[s], wotl + (size_t)bn * KTOT + kk, KTOT, tid);
        }
        __builtin_amdgcn_s_waitcnt(0);
        __syncthreads();
        mfma_ss(Ah[0], Al[0], Bh[0], Bl[0], acc, tid);
        mfma_ss(Ah[1], Al[1], Bh[1], Bl[1], acc, tid);
    }
    const int lane = tid & 63, w = tid >> 6;
    const int wm = (w & 1) * 64, wn = (w >> 1) * 32;
    const int fr = lane & 15, q = lane >> 4;
#pragma unroll
    for (int j = 0; j < 2; ++j) {
        const int col = bn + wn + 16 * j + fr;
#pragma unroll
        for (int i = 0; i < 4; ++i)
#pragma unroll
            for (int r = 0; r < 4; ++r) {
                const int row = bm + wm + 16 * i + 4 * q + r;
                ht[(size_t)row * DDIM + col] = tanhf(acc[i][j][r]);
            }
    }
}

// ---------------------------------------------------------------------------
extern "C" void kernel_launch(void* const* d_in, const int* in_sizes, int n_in,
                              void* d_out, int out_size, void* d_ws, size_t ws_size,
                              hipStream_t stream) {
    (void)in_sizes; (void)n_in; (void)out_size; (void)ws_size;
    const float* dec = (const float*)d_in[0];
    const float* enc = (const float*)d_in[1];
    const int* mask = (const int*)d_in[2];
    const float* Wa = (const float*)d_in[3];
    const float* ba = (const float*)d_in[4];
    const float* Wo = (const float*)d_in[5];

    float* h_tilde = (float*)d_out;
    float* attn = h_tilde + (size_t)BB * TT * DDIM;
    float* menerg = attn + (size_t)BB * TT * SS;

    // Workspace layout (bytes), total ~72.4 MB
    char* ws = (char*)d_ws;
    u16* decW_hi = (u16*)(ws);                       // 8192x1024 u16 = 16.78 MB
    u16* decW_lo = (u16*)(ws + 16777216);
    u16* dec_hi  = (u16*)(ws + 33554432);            // 8192x512
    u16* dec_lo  = (u16*)(ws + 41943040);
    u16* attn_hi = (u16*)(ws + 50331648);            // 8192x512
    u16* wa_hi   = (u16*)(ws + 67108864);            // 1024x512
    u16* wa_lo   = (u16*)(ws + 68157440);
    u16* wot_hi  = (u16*)(ws + 69206016);            // 512x1536
    u16* wot_lo  = (u16*)(ws + 70778880);
    float* decb  = (float*)(ws + 72351744);          // 8192 f32
    // wc planes alias decW planes (decW dead after k_energy)
    u16* wc_hi = decW_hi;
    u16* wc_lo = decW_lo;

    k_conv<<<(BB * TT * DDIM) / 4 / 256, 256, 0, stream>>>(dec, dec_hi, dec_lo);
    k_conv<<<(EE * DDIM) / 4 / 256, 256, 0, stream>>>(Wa, wa_hi, wa_lo);
    k_wot<<<dim3((EE + DDIM) / 64, DDIM / 64), 256, 0, stream>>>(Wo, wot_hi, wot_lo);
    k_decb<<<(BB * TT) / 4, 256, 0, stream>>>(dec, ba, decb);
    k_decw<<<dim3((BB * TT) / BM2, EE / BN), 256, 0, stream>>>(dec_hi, dec_lo, wa_hi, wa_lo,
                                                               decW_hi, decW_lo);
    k_energy<<<dim3(SS / BN, TT / BM2, BB), 256, 0, stream>>>(decW_hi, decW_lo, enc, mask, decb,
                                                              menerg);
    k_softmax<<<BB * TT, 128, 0, stream>>>(menerg, attn, attn_hi);
    k_ctx<<<dim3(EE / BN, 1, BB), 256, 0, stream>>>(attn_hi, enc, wc_hi, wc_lo);
    k_out<<<dim3((BB * TT) / BM, DDIM / BN), 256, 0, stream>>>(wc_hi, wc_lo, dec_hi, dec_lo,
                                                               wot_hi, wot_lo, h_tilde);
}

// Round 5
// 353.796 us; speedup vs baseline: 1.2736x; 1.0829x over previous
//
#include <hip/hip_runtime.h>
#include <cmath>

// Problem constants
#define BB 64
#define TT 128
#define SS 512
#define EE 1024
#define DDIM 512
#define NEG_INF_F (-1.0e10f)

// MFMA tiling
#define BM 128
#define BM2 64   // half-height block for grid-limited kernels (wave tile 32x32)
#define BN 64
#define BK 32
#define LDSTP 20   // padded layout row stride (dwords): 80 B rows -> b128-aligned, 2-way banks (free)
#define ROWU 32    // swizzled plane layout row stride in u16 (64 B/row)

typedef unsigned short u16;
typedef __attribute__((ext_vector_type(8))) short bf16x8;
typedef __attribute__((ext_vector_type(4))) float f32x4;

// ---------------------------------------------------------------------------
// fp32 -> bf16 split (hi = rne(f), lo = rne(f - hi)); ~2^-18 rel error
// ---------------------------------------------------------------------------
__device__ __forceinline__ unsigned bf16_rne(float f) {
    unsigned u = __float_as_uint(f);
    return (u + 0x7fffu + ((u >> 16) & 1u)) >> 16;
}
__device__ __forceinline__ void split2(float f, unsigned& h, unsigned& l) {
    h = bf16_rne(f);
    float fh = __uint_as_float(h << 16);
    l = bf16_rne(f - fh);
}

// Overflow-safe fast tanh: t = e^{-2|x|} in (0,1], r = (1-t)/(1+t)
__device__ __forceinline__ float fast_tanh(float x) {
    float t = __expf(-2.0f * fabsf(x));
    float r = __fdividef(1.0f - t, 1.0f + t);
    return copysignf(r, x);
}

// ---------------------------------------------------------------------------
// glds staging of a bf16 plane tile: ROWS rows x 32 bf16 (64 B/row), with the
// quad-swizzle chunk(q)->slot q^((r>>1)&3). Lane-linear LDS writes (16 B/lane).
// ---------------------------------------------------------------------------
template <int ROWS>
__device__ __forceinline__ void stage_glds(u16* lds, const u16* __restrict__ src,
                                           int ld, int tid) {
    const int w = tid >> 6, lane = tid & 63;
    const int rl = lane >> 2, p = lane & 3;
#pragma unroll
    for (int i = 0; i < ROWS / 64; ++i) {
        const int r0 = (w + 4 * i) * 16;
        const int r = r0 + rl;
        const int q = p ^ ((r >> 1) & 3);
        const u16* g = src + (size_t)r * ld + 8 * q;
        __builtin_amdgcn_global_load_lds(
            (const __attribute__((address_space(1))) unsigned*)g,
            (__attribute__((address_space(3))) unsigned*)(lds + r0 * ROWU),
            16, 0, 0);
    }
}

// Read a 16x16x32 fragment from the swizzled plane layout (one ds_read_b128)
__device__ __forceinline__ bf16x8 read_frag_sw(const u16* buf, int row, int q) {
    const int c = q ^ ((row >> 1) & 3);
    return *(const bf16x8*)(buf + row * ROWU + 8 * c);
}

// ---------------------------------------------------------------------------
// VALU staging of an NT fp32 operand (rows x BK, k contiguous) into padded
// hi/lo LDS (u32 = bf16 pair (2k,2k+1)). Used for enc in k_energy.
// ---------------------------------------------------------------------------
template <int ROWS>
__device__ __forceinline__ void stage_nt(unsigned* hi, unsigned* lo,
                                         const float* __restrict__ src, int ld, int tid) {
#pragma unroll
    for (int i = 0; i < ROWS / 32; ++i) {
        int s = tid + 256 * i;
        int r = s >> 3, kq = s & 7;
        float4 v = *(const float4*)(src + (size_t)r * ld + 4 * kq);
        unsigned h0, l0, h1, l1, h2, l2, h3, l3;
        split2(v.x, h0, l0); split2(v.y, h1, l1);
        split2(v.z, h2, l2); split2(v.w, h3, l3);
        *(uint2*)&hi[r * LDSTP + 2 * kq] = make_uint2(h0 | (h1 << 16), h2 | (h3 << 16));
        *(uint2*)&lo[r * LDSTP + 2 * kq] = make_uint2(l0 | (l1 << 16), l2 | (l3 << 16));
    }
}

// ---------------------------------------------------------------------------
// Single-plane VALU staging of a transposed fp32 B tile (k_ctx, 32 k-rows):
// global [32 k][BN n] -> padded LDS rows = n, bf16 rne only (no lo plane).
// ---------------------------------------------------------------------------
__device__ __forceinline__ void stage_tr1(unsigned* hi, const float* __restrict__ src,
                                          int ld, int tid) {
    int eq = tid & 15;   // n quad
    int sp = tid >> 4;   // k pair
    const float* p = src + (size_t)(2 * sp) * ld + 4 * eq;
    float4 va = *(const float4*)p;
    float4 vb = *(const float4*)(p + ld);
    float av[4] = {va.x, va.y, va.z, va.w};
    float bv[4] = {vb.x, vb.y, vb.z, vb.w};
#pragma unroll
    for (int c = 0; c < 4; ++c) {
        hi[(4 * eq + c) * LDSTP + sp] = bf16_rne(av[c]) | (bf16_rne(bv[c]) << 16);
    }
}

// Read a fragment from the padded layout (aligned b128: 80r+16q bytes)
__device__ __forceinline__ bf16x8 read_frag_pad(const unsigned* buf, int row, int q) {
    return *(const bf16x8*)(buf + row * LDSTP + 4 * q);
}

// ---------------------------------------------------------------------------
// MFMA cores
// ---------------------------------------------------------------------------
// 64x64 block, split-split (k_decw): 3 MFMAs per tile
__device__ __forceinline__ void mfma_ss64(const u16* Ah, const u16* Al,
                                          const u16* Bh, const u16* Bl,
                                          f32x4 acc[2][2], int tid) {
    const int lane = tid & 63, w = tid >> 6;
    const int wm = (w & 1) * 32, wn = (w >> 1) * 32;
    const int fr = lane & 15, q = lane >> 4;
    bf16x8 ah[2], al[2];
#pragma unroll
    for (int i = 0; i < 2; ++i) {
        ah[i] = read_frag_sw(Ah, wm + 16 * i + fr, q);
        al[i] = read_frag_sw(Al, wm + 16 * i + fr, q);
    }
#pragma unroll
    for (int j = 0; j < 2; ++j) {
        bf16x8 bh = read_frag_sw(Bh, wn + 16 * j + fr, q);
        bf16x8 bl = read_frag_sw(Bl, wn + 16 * j + fr, q);
#pragma unroll
        for (int i = 0; i < 2; ++i) {
            acc[i][j] = __builtin_amdgcn_mfma_f32_16x16x32_bf16(ah[i], bh, acc[i][j], 0, 0, 0);
            acc[i][j] = __builtin_amdgcn_mfma_f32_16x16x32_bf16(ah[i], bl, acc[i][j], 0, 0, 0);
            acc[i][j] = __builtin_amdgcn_mfma_f32_16x16x32_bf16(al[i], bh, acc[i][j], 0, 0, 0);
        }
    }
}

// 64x64 block, split-A / padded-split-B (k_energy): 3 MFMAs per tile
__device__ __forceinline__ void mfma_sp64(const u16* Ah, const u16* Al,
                                          const unsigned* Bh, const unsigned* Bl,
                                          f32x4 acc[2][2], int tid) {
    const int lane = tid & 63, w = tid >> 6;
    const int wm = (w & 1) * 32, wn = (w >> 1) * 32;
    const int fr = lane & 15, q = lane >> 4;
    bf16x8 ah[2], al[2];
#pragma unroll
    for (int i = 0; i < 2; ++i) {
        ah[i] = read_frag_sw(Ah, wm + 16 * i + fr, q);
        al[i] = read_frag_sw(Al, wm + 16 * i + fr, q);
    }
#pragma unroll
    for (int j = 0; j < 2; ++j) {
        bf16x8 bh = read_frag_pad(Bh, wn + 16 * j + fr, q);
        bf16x8 bl = read_frag_pad(Bl, wn + 16 * j + fr, q);
#pragma unroll
        for (int i = 0; i < 2; ++i) {
            acc[i][j] = __builtin_amdgcn_mfma_f32_16x16x32_bf16(ah[i], bh, acc[i][j], 0, 0, 0);
            acc[i][j] = __builtin_amdgcn_mfma_f32_16x16x32_bf16(ah[i], bl, acc[i][j], 0, 0, 0);
            acc[i][j] = __builtin_amdgcn_mfma_f32_16x16x32_bf16(al[i], bh, acc[i][j], 0, 0, 0);
        }
    }
}

// 128x64 block, single-bf16 A (sw plane) x single-bf16 B (padded) — k_ctx
__device__ __forceinline__ void mfma_sp1(const u16* Ah, const unsigned* Bh,
                                         f32x4 acc[4][2], int tid) {
    const int lane = tid & 63, w = tid >> 6;
    const int wm = (w & 1) * 64, wn = (w >> 1) * 32;
    const int fr = lane & 15, q = lane >> 4;
    bf16x8 ah[4];
#pragma unroll
    for (int i = 0; i < 4; ++i) ah[i] = read_frag_sw(Ah, wm + 16 * i + fr, q);
#pragma unroll
    for (int j = 0; j < 2; ++j) {
        bf16x8 bh = read_frag_pad(Bh, wn + 16 * j + fr, q);
#pragma unroll
        for (int i = 0; i < 4; ++i)
            acc[i][j] = __builtin_amdgcn_mfma_f32_16x16x32_bf16(ah[i], bh, acc[i][j], 0, 0, 0);
    }
}

// 128x64 block, single-bf16 A (sw plane) x single-bf16 B (sw plane) — k_out
__device__ __forceinline__ void mfma_s1(const u16* Ah, const u16* Bh,
                                        f32x4 acc[4][2], int tid) {
    const int lane = tid & 63, w = tid >> 6;
    const int wm = (w & 1) * 64, wn = (w >> 1) * 32;
    const int fr = lane & 15, q = lane >> 4;
    bf16x8 ah[4];
#pragma unroll
    for (int i = 0; i < 4; ++i) ah[i] = read_frag_sw(Ah, wm + 16 * i + fr, q);
#pragma unroll
    for (int j = 0; j < 2; ++j) {
        bf16x8 bh = read_frag_sw(Bh, wn + 16 * j + fr, q);
#pragma unroll
        for (int i = 0; i < 4; ++i)
            acc[i][j] = __builtin_amdgcn_mfma_f32_16x16x32_bf16(ah[i], bh, acc[i][j], 0, 0, 0);
    }
}

// ---------------------------------------------------------------------------
// Convert kernels
// ---------------------------------------------------------------------------
__global__ __launch_bounds__(256) void k_conv(const float* __restrict__ src,
                                              u16* __restrict__ hi, u16* __restrict__ lo) {
    const int i = blockIdx.x * 256 + threadIdx.x;
    float4 v = ((const float4*)src)[i];
    unsigned h0, l0, h1, l1, h2, l2, h3, l3;
    split2(v.x, h0, l0); split2(v.y, h1, l1);
    split2(v.z, h2, l2); split2(v.w, h3, l3);
    ((ushort4*)hi)[i] = make_ushort4((u16)h0, (u16)h1, (u16)h2, (u16)h3);
    ((ushort4*)lo)[i] = make_ushort4((u16)l0, (u16)l1, (u16)l2, (u16)l3);
}

// Wo [1536,512] -> WoT hi plane [512,1536] (single bf16: k_out is all-single)
__global__ __launch_bounds__(256) void k_wot(const float* __restrict__ Wo,
                                             u16* __restrict__ thi) {
    __shared__ float t[64][65];
    const int tid = threadIdx.x;
    const int r0 = blockIdx.x * 64;  // Wo row tile (k)
    const int c0 = blockIdx.y * 64;  // Wo col tile (n)
    const int rr = tid >> 4, cc = tid & 15;
#pragma unroll
    for (int i = 0; i < 4; ++i) {
        float4 v = *(const float4*)(Wo + (size_t)(r0 + rr + 16 * i) * DDIM + c0 + 4 * cc);
        t[rr + 16 * i][4 * cc + 0] = v.x;
        t[rr + 16 * i][4 * cc + 1] = v.y;
        t[rr + 16 * i][4 * cc + 2] = v.z;
        t[rr + 16 * i][4 * cc + 3] = v.w;
    }
    __syncthreads();
#pragma unroll
    for (int i = 0; i < 4; ++i) {
        const int oc = rr + 16 * i;  // WoT row (= Wo col)
        size_t off = (size_t)(c0 + oc) * (EE + DDIM) + r0 + 4 * cc;
        *(ushort4*)(thi + off) = make_ushort4((u16)bf16_rne(t[4 * cc + 0][oc]),
                                              (u16)bf16_rne(t[4 * cc + 1][oc]),
                                              (u16)bf16_rne(t[4 * cc + 2][oc]),
                                              (u16)bf16_rne(t[4 * cc + 3][oc]));
    }
}

// ---------------------------------------------------------------------------
// K1: decW = dec @ W_attn^T (NT, M=8192, N=1024, K=512) -> hi/lo planes
// 64x64 block, BK=64 as 2x32 subtiles.
// ---------------------------------------------------------------------------
__global__ __launch_bounds__(256) void k_decw(const u16* __restrict__ Ahp, const u16* __restrict__ Alp,
                                              const u16* __restrict__ Bhp, const u16* __restrict__ Blp,
                                              u16* __restrict__ Chi, u16* __restrict__ Clo) {
    __shared__ u16 Ah[2][BM2 * ROWU], Al[2][BM2 * ROWU], Bh[2][BN * ROWU], Bl[2][BN * ROWU];
    const int tid = threadIdx.x;
    const int bm = blockIdx.x * BM2, bn = blockIdx.y * BN;  // x = m for B-tile L2 reuse
    f32x4 acc[2][2] = {};
    for (int k0 = 0; k0 < DDIM; k0 += 2 * BK) {
        __syncthreads();
        stage_glds<BM2>(Ah[0], Ahp + (size_t)bm * DDIM + k0, DDIM, tid);
        stage_glds<BM2>(Al[0], Alp + (size_t)bm * DDIM + k0, DDIM, tid);
        stage_glds<BM2>(Ah[1], Ahp + (size_t)bm * DDIM + k0 + BK, DDIM, tid);
        stage_glds<BM2>(Al[1], Alp + (size_t)bm * DDIM + k0 + BK, DDIM, tid);
        stage_glds<BN>(Bh[0], Bhp + (size_t)bn * DDIM + k0, DDIM, tid);
        stage_glds<BN>(Bl[0], Blp + (size_t)bn * DDIM + k0, DDIM, tid);
        stage_glds<BN>(Bh[1], Bhp + (size_t)bn * DDIM + k0 + BK, DDIM, tid);
        stage_glds<BN>(Bl[1], Blp + (size_t)bn * DDIM + k0 + BK, DDIM, tid);
        __builtin_amdgcn_s_waitcnt(0);
        __syncthreads();
        mfma_ss64(Ah[0], Al[0], Bh[0], Bl[0], acc, tid);
        mfma_ss64(Ah[1], Al[1], Bh[1], Bl[1], acc, tid);
    }
    const int lane = tid & 63, w = tid >> 6;
    const int wm = (w & 1) * 32, wn = (w >> 1) * 32;
    const int fr = lane & 15, q = lane >> 4;
#pragma unroll
    for (int j = 0; j < 2; ++j) {
        const int col = bn + wn + 16 * j + fr;
#pragma unroll
        for (int i = 0; i < 2; ++i)
#pragma unroll
            for (int r = 0; r < 4; ++r) {
                const int row = bm + wm + 16 * i + 4 * q + r;
                unsigned h, l;
                split2(acc[i][j][r], h, l);
                Chi[(size_t)row * EE + col] = (u16)h;
                Clo[(size_t)row * EE + col] = (u16)l;
            }
    }
}

// ---------------------------------------------------------------------------
// K1b: decb[m] = dec[m,:] . b_attn
// ---------------------------------------------------------------------------
__global__ __launch_bounds__(256) void k_decb(const float* __restrict__ dec,
                                              const float* __restrict__ ba,
                                              float* __restrict__ decb) {
    const int row = blockIdx.x * 4 + (threadIdx.x >> 6);
    const int lane = threadIdx.x & 63;
    const float* x = dec + (size_t)row * DDIM;
    float s = 0.f;
#pragma unroll
    for (int i = 0; i < 8; ++i) {
        int idx = lane + i * 64;
        s += x[idx] * ba[idx];
    }
#pragma unroll
    for (int off = 32; off >= 1; off >>= 1) s += __shfl_xor(s, off, 64);
    if (lane == 0) decb[row] = s;
}

// ---------------------------------------------------------------------------
// K2: masked energies (NT batched, M=T=128, N=S, K=E) + bias + mask
// 64x64 block (grid 1024 -> 4 blocks/CU), BK=64 (two 32-subtiles per barrier
// pair, 16 regions). Best-measured form, unchanged.
// ---------------------------------------------------------------------------
__global__ __launch_bounds__(256) void k_energy(const u16* __restrict__ Ahp, const u16* __restrict__ Alp,
                                                const float* __restrict__ enc,
                                                const int* __restrict__ mask,
                                                const float* __restrict__ decb,
                                                float* __restrict__ menerg) {
    const int b = blockIdx.z;
    const int bn = blockIdx.x * BN;
    const int bm = blockIdx.y * BM2;
    __shared__ u16 Ah[2][BM2 * ROWU], Al[2][BM2 * ROWU];
    __shared__ unsigned Bh[2][BN * LDSTP], Bl[2][BN * LDSTP];
    const int tid = threadIdx.x;
    const u16* Abh = Ahp + (size_t)b * TT * EE + (size_t)bm * EE;
    const u16* Abl = Alp + (size_t)b * TT * EE + (size_t)bm * EE;
    const float* Bt = enc + (size_t)b * SS * EE + (size_t)bn * EE;
    f32x4 acc[2][2] = {};
    for (int k0 = 0; k0 < EE; k0 += 2 * BK) {
        __syncthreads();
        stage_glds<BM2>(Ah[0], Abh + k0, EE, tid);
        stage_glds<BM2>(Al[0], Abl + k0, EE, tid);
        stage_glds<BM2>(Ah[1], Abh + k0 + BK, EE, tid);
        stage_glds<BM2>(Al[1], Abl + k0 + BK, EE, tid);
        stage_nt<BN>(Bh[0], Bl[0], Bt + k0, EE, tid);
        stage_nt<BN>(Bh[1], Bl[1], Bt + k0 + BK, EE, tid);
        __builtin_amdgcn_s_waitcnt(0);
        __syncthreads();
        mfma_sp64(Ah[0], Al[0], Bh[0], Bl[0], acc, tid);
        mfma_sp64(Ah[1], Al[1], Bh[1], Bl[1], acc, tid);
    }
    const int lane = tid & 63, w = tid >> 6;
    const int wm = (w & 1) * 32, wn = (w >> 1) * 32;
    const int fr = lane & 15, q = lane >> 4;
    const int* mb = mask + (size_t)b * SS;
    const float* dbp = decb + (size_t)b * TT + bm;
    float* Crow = menerg + (size_t)b * TT * SS + (size_t)bm * SS;
    float db[2][4];
#pragma unroll
    for (int i = 0; i < 2; ++i) {
        float4 d4 = *(const float4*)(dbp + wm + 16 * i + 4 * q);
        db[i][0] = d4.x; db[i][1] = d4.y; db[i][2] = d4.z; db[i][3] = d4.w;
    }
#pragma unroll
    for (int j = 0; j < 2; ++j) {
        const int col = bn + wn + 16 * j + fr;
        const int mk = mb[col];
#pragma unroll
        for (int i = 0; i < 2; ++i)
#pragma unroll
            for (int r = 0; r < 4; ++r) {
                const int row = wm + 16 * i + 4 * q + r;
                Crow[(size_t)row * SS + col] = mk ? acc[i][j][r] + db[i][r] : NEG_INF_F;
            }
    }
}

// ---------------------------------------------------------------------------
// K3: softmax over S=512 -> attn fp32 (output) + attn hi plane (bf16 rne)
// ---------------------------------------------------------------------------
__global__ __launch_bounds__(128) void k_softmax(const float* __restrict__ me,
                                                 float* __restrict__ attn,
                                                 u16* __restrict__ ahi) {
    const int row = blockIdx.x;
    const int tid = threadIdx.x;
    const float4 v = ((const float4*)(me + (size_t)row * SS))[tid];
    float m = fmaxf(fmaxf(v.x, v.y), fmaxf(v.z, v.w));
#pragma unroll
    for (int off = 32; off >= 1; off >>= 1) m = fmaxf(m, __shfl_xor(m, off, 64));
    __shared__ float redm[2];
    __shared__ float reds[2];
    const int wv = tid >> 6, lane = tid & 63;
    if (lane == 0) redm[wv] = m;
    __syncthreads();
    m = fmaxf(redm[0], redm[1]);
    float e0 = __expf(v.x - m), e1 = __expf(v.y - m);
    float e2 = __expf(v.z - m), e3 = __expf(v.w - m);
    float s = (e0 + e1) + (e2 + e3);
#pragma unroll
    for (int off = 32; off >= 1; off >>= 1) s += __shfl_xor(s, off, 64);
    if (lane == 0) reds[wv] = s;
    __syncthreads();
    s = reds[0] + reds[1];
    const float inv = 1.0f / s;
    float o0 = e0 * inv, o1 = e1 * inv, o2 = e2 * inv, o3 = e3 * inv;
    ((float4*)(attn + (size_t)row * SS))[tid] = make_float4(o0, o1, o2, o3);
    ((ushort4*)(ahi + (size_t)row * SS))[tid] =
        make_ushort4((u16)bf16_rne(o0), (u16)bf16_rne(o1),
                     (u16)bf16_rne(o2), (u16)bf16_rne(o3));
}

// ---------------------------------------------------------------------------
// K4: wc = attn @ enc (NN batched, M=T, N=E, K=S) -> wc hi plane ONLY
// (k_out is now all-single-bf16; wc_lo dead). 1 MFMA per tile, BK=64 subtiles.
// ---------------------------------------------------------------------------
__global__ __launch_bounds__(256) void k_ctx(const u16* __restrict__ Ahp,
                                             const float* __restrict__ enc,
                                             u16* __restrict__ Chi) {
    const int b = blockIdx.z;
    const int bn = blockIdx.x * BN;  // over E
    __shared__ u16 Ah[2][BM * ROWU];
    __shared__ unsigned Bh[2][BN * LDSTP];
    const int tid = threadIdx.x;
    const u16* Abh = Ahp + (size_t)b * TT * SS;
    const float* Bm = enc + (size_t)b * SS * EE + bn;
    f32x4 acc[4][2] = {};
    for (int k0 = 0; k0 < SS; k0 += 2 * BK) {
        __syncthreads();
        stage_glds<BM>(Ah[0], Abh + k0, SS, tid);
        stage_glds<BM>(Ah[1], Abh + k0 + BK, SS, tid);
        stage_tr1(Bh[0], Bm + (size_t)k0 * EE, EE, tid);
        stage_tr1(Bh[1], Bm + (size_t)(k0 + BK) * EE, EE, tid);
        __builtin_amdgcn_s_waitcnt(0);
        __syncthreads();
        mfma_sp1(Ah[0], Bh[0], acc, tid);
        mfma_sp1(Ah[1], Bh[1], acc, tid);
    }
    const int lane = tid & 63, w = tid >> 6;
    const int wm = (w & 1) * 64, wn = (w >> 1) * 32;
    const int fr = lane & 15, q = lane >> 4;
    u16* Ch = Chi + (size_t)b * TT * EE;
#pragma unroll
    for (int j = 0; j < 2; ++j) {
        const int col = bn + wn + 16 * j + fr;
#pragma unroll
        for (int i = 0; i < 4; ++i)
#pragma unroll
            for (int r = 0; r < 4; ++r) {
                const int row = wm + 16 * i + 4 * q + r;
                Ch[(size_t)row * EE + col] = (u16)bf16_rne(acc[i][j][r]);
            }
    }
}

// ---------------------------------------------------------------------------
// K5: h_tilde = tanh([wc | dec] @ W_out), ALL-SINGLE-bf16 (pre-act err ~4e-3,
// tanh contracts): 1 MFMA per tile (3x fewer), half the staging. BK=64.
// ---------------------------------------------------------------------------
__global__ __launch_bounds__(256) void k_out(const u16* __restrict__ wch,
                                             const u16* __restrict__ dech,
                                             const u16* __restrict__ woth,
                                             float* __restrict__ ht) {
    __shared__ u16 Ah[2][BM * ROWU], Bh[2][BN * ROWU];
    const int tid = threadIdx.x;
    const int bm = blockIdx.x * BM, bn = blockIdx.y * BN;  // x = m for B-tile reuse
    const int KTOT = EE + DDIM;
    f32x4 acc[4][2] = {};
    for (int k0 = 0; k0 < KTOT; k0 += 2 * BK) {
        __syncthreads();
#pragma unroll
        for (int s = 0; s < 2; ++s) {
            const int kk = k0 + BK * s;
            const u16* ah;
            int ld;
            if (kk < EE) {
                ah = wch + (size_t)bm * EE + kk;
                ld = EE;
            } else {
                ah = dech + (size_t)bm * DDIM + (kk - EE);
                ld = DDIM;
            }
            stage_glds<BM>(Ah[s], ah, ld, tid);
            stage_glds<BN>(Bh[s], woth + (size_t)bn * KTOT + kk, KTOT, tid);
        }
        __builtin_amdgcn_s_waitcnt(0);
        __syncthreads();
        mfma_s1(Ah[0], Bh[0], acc, tid);
        mfma_s1(Ah[1], Bh[1], acc, tid);
    }
    const int lane = tid & 63, w = tid >> 6;
    const int wm = (w & 1) * 64, wn = (w >> 1) * 32;
    const int fr = lane & 15, q = lane >> 4;
#pragma unroll
    for (int j = 0; j < 2; ++j) {
        const int col = bn + wn + 16 * j + fr;
#pragma unroll
        for (int i = 0; i < 4; ++i)
#pragma unroll
            for (int r = 0; r < 4; ++r) {
                const int row = bm + wm + 16 * i + 4 * q + r;
                ht[(size_t)row * DDIM + col] = fast_tanh(acc[i][j][r]);
            }
    }
}

// ---------------------------------------------------------------------------
extern "C" void kernel_launch(void* const* d_in, const int* in_sizes, int n_in,
                              void* d_out, int out_size, void* d_ws, size_t ws_size,
                              hipStream_t stream) {
    (void)in_sizes; (void)n_in; (void)out_size; (void)ws_size;
    const float* dec = (const float*)d_in[0];
    const float* enc = (const float*)d_in[1];
    const int* mask = (const int*)d_in[2];
    const float* Wa = (const float*)d_in[3];
    const float* ba = (const float*)d_in[4];
    const float* Wo = (const float*)d_in[5];

    float* h_tilde = (float*)d_out;
    float* attn = h_tilde + (size_t)BB * TT * DDIM;
    float* menerg = attn + (size_t)BB * TT * SS;

    // Workspace layout (bytes), total ~72.4 MB
    char* ws = (char*)d_ws;
    u16* decW_hi = (u16*)(ws);                       // 8192x1024 u16 = 16.78 MB
    u16* decW_lo = (u16*)(ws + 16777216);
    u16* dec_hi  = (u16*)(ws + 33554432);            // 8192x512
    u16* dec_lo  = (u16*)(ws + 41943040);
    u16* attn_hi = (u16*)(ws + 50331648);            // 8192x512
    u16* wa_hi   = (u16*)(ws + 67108864);            // 1024x512
    u16* wa_lo   = (u16*)(ws + 68157440);
    u16* wot_hi  = (u16*)(ws + 69206016);            // 512x1536
    float* decb  = (float*)(ws + 72351744);          // 8192 f32
    // wc plane aliases decW_hi (decW dead after k_energy)
    u16* wc_hi = decW_hi;

    k_conv<<<(BB * TT * DDIM) / 4 / 256, 256, 0, stream>>>(dec, dec_hi, dec_lo);
    k_conv<<<(EE * DDIM) / 4 / 256, 256, 0, stream>>>(Wa, wa_hi, wa_lo);
    k_wot<<<dim3((EE + DDIM) / 64, DDIM / 64), 256, 0, stream>>>(Wo, wot_hi);
    k_decb<<<(BB * TT) / 4, 256, 0, stream>>>(dec, ba, decb);
    k_decw<<<dim3((BB * TT) / BM2, EE / BN), 256, 0, stream>>>(dec_hi, dec_lo, wa_hi, wa_lo,
                                                               decW_hi, decW_lo);
    k_energy<<<dim3(SS / BN, TT / BM2, BB), 256, 0, stream>>>(decW_hi, decW_lo, enc, mask, decb,
                                                              menerg);
    k_softmax<<<BB * TT, 128, 0, stream>>>(menerg, attn, attn_hi);
    k_ctx<<<dim3(EE / BN, 1, BB), 256, 0, stream>>>(attn_hi, enc, wc_hi);
    k_out<<<dim3((BB * TT) / BM, DDIM / BN), 256, 0, stream>>>(wc_hi, dec_hi, wot_hi, h_tilde);
}

// Round 6
// 337.995 us; speedup vs baseline: 1.3331x; 1.0468x over previous
//
#include <hip/hip_runtime.h>
#include <cmath>

// Problem constants
#define BB 64
#define TT 128
#define SS 512
#define EE 1024
#define DDIM 512
#define NEG_INF_F (-1.0e10f)

// MFMA tiling
#define BM 128
#define BM2 64   // half-height block for grid-limited kernels (wave tile 32x32)
#define BN 64
#define BK 32
#define LDSTP 20   // padded layout row stride (dwords): 80 B rows -> b128-aligned, 2-way banks (free)
#define ROWU 32    // swizzled plane layout row stride in u16 (64 B/row)

typedef unsigned short u16;
typedef __attribute__((ext_vector_type(8))) short bf16x8;
typedef __attribute__((ext_vector_type(4))) float f32x4;

// ---------------------------------------------------------------------------
// fp32 -> bf16 split (hi = rne(f), lo = rne(f - hi)); ~2^-18 rel error
// ---------------------------------------------------------------------------
__device__ __forceinline__ unsigned bf16_rne(float f) {
    unsigned u = __float_as_uint(f);
    return (u + 0x7fffu + ((u >> 16) & 1u)) >> 16;
}
__device__ __forceinline__ void split2(float f, unsigned& h, unsigned& l) {
    h = bf16_rne(f);
    float fh = __uint_as_float(h << 16);
    l = bf16_rne(f - fh);
}

// Overflow-safe fast tanh: t = e^{-2|x|} in (0,1], r = (1-t)/(1+t)
__device__ __forceinline__ float fast_tanh(float x) {
    float t = __expf(-2.0f * fabsf(x));
    float r = __fdividef(1.0f - t, 1.0f + t);
    return copysignf(r, x);
}

// ---------------------------------------------------------------------------
// glds staging of a bf16 plane tile: ROWS rows x 32 bf16 (64 B/row), with the
// quad-swizzle chunk(q)->slot q^((r>>1)&3). Lane-linear LDS writes (16 B/lane).
// ---------------------------------------------------------------------------
template <int ROWS>
__device__ __forceinline__ void stage_glds(u16* lds, const u16* __restrict__ src,
                                           int ld, int tid) {
    const int w = tid >> 6, lane = tid & 63;
    const int rl = lane >> 2, p = lane & 3;
#pragma unroll
    for (int i = 0; i < ROWS / 64; ++i) {
        const int r0 = (w + 4 * i) * 16;
        const int r = r0 + rl;
        const int q = p ^ ((r >> 1) & 3);
        const u16* g = src + (size_t)r * ld + 8 * q;
        __builtin_amdgcn_global_load_lds(
            (const __attribute__((address_space(1))) unsigned*)g,
            (__attribute__((address_space(3))) unsigned*)(lds + r0 * ROWU),
            16, 0, 0);
    }
}

// Read a 16x16x32 fragment from the swizzled plane layout (one ds_read_b128)
__device__ __forceinline__ bf16x8 read_frag_sw(const u16* buf, int row, int q) {
    const int c = q ^ ((row >> 1) & 3);
    return *(const bf16x8*)(buf + row * ROWU + 8 * c);
}

// ---------------------------------------------------------------------------
// VALU staging of an NT fp32 operand (rows x BK, k contiguous) into padded
// hi/lo LDS (u32 = bf16 pair (2k,2k+1)). Used for enc in k_energy.
// ---------------------------------------------------------------------------
template <int ROWS>
__device__ __forceinline__ void stage_nt(unsigned* hi, unsigned* lo,
                                         const float* __restrict__ src, int ld, int tid) {
#pragma unroll
    for (int i = 0; i < ROWS / 32; ++i) {
        int s = tid + 256 * i;
        int r = s >> 3, kq = s & 7;
        float4 v = *(const float4*)(src + (size_t)r * ld + 4 * kq);
        unsigned h0, l0, h1, l1, h2, l2, h3, l3;
        split2(v.x, h0, l0); split2(v.y, h1, l1);
        split2(v.z, h2, l2); split2(v.w, h3, l3);
        *(uint2*)&hi[r * LDSTP + 2 * kq] = make_uint2(h0 | (h1 << 16), h2 | (h3 << 16));
        *(uint2*)&lo[r * LDSTP + 2 * kq] = make_uint2(l0 | (l1 << 16), l2 | (l3 << 16));
    }
}

// ---------------------------------------------------------------------------
// Single-plane VALU staging of a transposed fp32 B tile (k_ctx, 32 k-rows):
// global [32 k][BN n] -> padded LDS rows = n, bf16 rne only (no lo plane).
// ---------------------------------------------------------------------------
__device__ __forceinline__ void stage_tr1(unsigned* hi, const float* __restrict__ src,
                                          int ld, int tid) {
    int eq = tid & 15;   // n quad
    int sp = tid >> 4;   // k pair
    const float* p = src + (size_t)(2 * sp) * ld + 4 * eq;
    float4 va = *(const float4*)p;
    float4 vb = *(const float4*)(p + ld);
    float av[4] = {va.x, va.y, va.z, va.w};
    float bv[4] = {vb.x, vb.y, vb.z, vb.w};
#pragma unroll
    for (int c = 0; c < 4; ++c) {
        hi[(4 * eq + c) * LDSTP + sp] = bf16_rne(av[c]) | (bf16_rne(bv[c]) << 16);
    }
}

// Read a fragment from the padded layout (aligned b128: 80r+16q bytes)
__device__ __forceinline__ bf16x8 read_frag_pad(const unsigned* buf, int row, int q) {
    return *(const bf16x8*)(buf + row * LDSTP + 4 * q);
}

// ---------------------------------------------------------------------------
// MFMA cores
// ---------------------------------------------------------------------------
// 64x64 block, single-A (sw) x split-B (sw) — k_decw: 2 MFMAs per tile
__device__ __forceinline__ void mfma_sb64(const u16* Ah, const u16* Bh, const u16* Bl,
                                          f32x4 acc[2][2], int tid) {
    const int lane = tid & 63, w = tid >> 6;
    const int wm = (w & 1) * 32, wn = (w >> 1) * 32;
    const int fr = lane & 15, q = lane >> 4;
    bf16x8 ah[2];
#pragma unroll
    for (int i = 0; i < 2; ++i) ah[i] = read_frag_sw(Ah, wm + 16 * i + fr, q);
#pragma unroll
    for (int j = 0; j < 2; ++j) {
        bf16x8 bh = read_frag_sw(Bh, wn + 16 * j + fr, q);
        bf16x8 bl = read_frag_sw(Bl, wn + 16 * j + fr, q);
#pragma unroll
        for (int i = 0; i < 2; ++i) {
            acc[i][j] = __builtin_amdgcn_mfma_f32_16x16x32_bf16(ah[i], bh, acc[i][j], 0, 0, 0);
            acc[i][j] = __builtin_amdgcn_mfma_f32_16x16x32_bf16(ah[i], bl, acc[i][j], 0, 0, 0);
        }
    }
}

// 64x64 block, single-A (sw) x padded-split-B — k_energy: 2 MFMAs per tile
__device__ __forceinline__ void mfma_sbp64(const u16* Ah,
                                           const unsigned* Bh, const unsigned* Bl,
                                           f32x4 acc[2][2], int tid) {
    const int lane = tid & 63, w = tid >> 6;
    const int wm = (w & 1) * 32, wn = (w >> 1) * 32;
    const int fr = lane & 15, q = lane >> 4;
    bf16x8 ah[2];
#pragma unroll
    for (int i = 0; i < 2; ++i) ah[i] = read_frag_sw(Ah, wm + 16 * i + fr, q);
#pragma unroll
    for (int j = 0; j < 2; ++j) {
        bf16x8 bh = read_frag_pad(Bh, wn + 16 * j + fr, q);
        bf16x8 bl = read_frag_pad(Bl, wn + 16 * j + fr, q);
#pragma unroll
        for (int i = 0; i < 2; ++i) {
            acc[i][j] = __builtin_amdgcn_mfma_f32_16x16x32_bf16(ah[i], bh, acc[i][j], 0, 0, 0);
            acc[i][j] = __builtin_amdgcn_mfma_f32_16x16x32_bf16(ah[i], bl, acc[i][j], 0, 0, 0);
        }
    }
}

// 128x64 block, single-bf16 A (sw plane) x single-bf16 B (padded) — k_ctx
__device__ __forceinline__ void mfma_sp1(const u16* Ah, const unsigned* Bh,
                                         f32x4 acc[4][2], int tid) {
    const int lane = tid & 63, w = tid >> 6;
    const int wm = (w & 1) * 64, wn = (w >> 1) * 32;
    const int fr = lane & 15, q = lane >> 4;
    bf16x8 ah[4];
#pragma unroll
    for (int i = 0; i < 4; ++i) ah[i] = read_frag_sw(Ah, wm + 16 * i + fr, q);
#pragma unroll
    for (int j = 0; j < 2; ++j) {
        bf16x8 bh = read_frag_pad(Bh, wn + 16 * j + fr, q);
#pragma unroll
        for (int i = 0; i < 4; ++i)
            acc[i][j] = __builtin_amdgcn_mfma_f32_16x16x32_bf16(ah[i], bh, acc[i][j], 0, 0, 0);
    }
}

// 128x64 block, single-bf16 A (sw plane) x single-bf16 B (sw plane) — k_out
__device__ __forceinline__ void mfma_s1(const u16* Ah, const u16* Bh,
                                        f32x4 acc[4][2], int tid) {
    const int lane = tid & 63, w = tid >> 6;
    const int wm = (w & 1) * 64, wn = (w >> 1) * 32;
    const int fr = lane & 15, q = lane >> 4;
    bf16x8 ah[4];
#pragma unroll
    for (int i = 0; i < 4; ++i) ah[i] = read_frag_sw(Ah, wm + 16 * i + fr, q);
#pragma unroll
    for (int j = 0; j < 2; ++j) {
        bf16x8 bh = read_frag_sw(Bh, wn + 16 * j + fr, q);
#pragma unroll
        for (int i = 0; i < 4; ++i)
            acc[i][j] = __builtin_amdgcn_mfma_f32_16x16x32_bf16(ah[i], bh, acc[i][j], 0, 0, 0);
    }
}

// ---------------------------------------------------------------------------
// Convert kernels
// ---------------------------------------------------------------------------
// hi/lo split planes (Wa)
__global__ __launch_bounds__(256) void k_conv(const float* __restrict__ src,
                                              u16* __restrict__ hi, u16* __restrict__ lo) {
    const int i = blockIdx.x * 256 + threadIdx.x;
    float4 v = ((const float4*)src)[i];
    unsigned h0, l0, h1, l1, h2, l2, h3, l3;
    split2(v.x, h0, l0); split2(v.y, h1, l1);
    split2(v.z, h2, l2); split2(v.w, h3, l3);
    ((ushort4*)hi)[i] = make_ushort4((u16)h0, (u16)h1, (u16)h2, (u16)h3);
    ((ushort4*)lo)[i] = make_ushort4((u16)l0, (u16)l1, (u16)l2, (u16)l3);
}

// hi plane only (dec: lo plane dead — k_decw is 2-MFMA, k_out all-single)
__global__ __launch_bounds__(256) void k_conv1(const float* __restrict__ src,
                                               u16* __restrict__ hi) {
    const int i = blockIdx.x * 256 + threadIdx.x;
    float4 v = ((const float4*)src)[i];
    ((ushort4*)hi)[i] = make_ushort4((u16)bf16_rne(v.x), (u16)bf16_rne(v.y),
                                     (u16)bf16_rne(v.z), (u16)bf16_rne(v.w));
}

// Wo [1536,512] -> WoT hi plane [512,1536] (single bf16: k_out is all-single)
__global__ __launch_bounds__(256) void k_wot(const float* __restrict__ Wo,
                                             u16* __restrict__ thi) {
    __shared__ float t[64][65];
    const int tid = threadIdx.x;
    const int r0 = blockIdx.x * 64;  // Wo row tile (k)
    const int c0 = blockIdx.y * 64;  // Wo col tile (n)
    const int rr = tid >> 4, cc = tid & 15;
#pragma unroll
    for (int i = 0; i < 4; ++i) {
        float4 v = *(const float4*)(Wo + (size_t)(r0 + rr + 16 * i) * DDIM + c0 + 4 * cc);
        t[rr + 16 * i][4 * cc + 0] = v.x;
        t[rr + 16 * i][4 * cc + 1] = v.y;
        t[rr + 16 * i][4 * cc + 2] = v.z;
        t[rr + 16 * i][4 * cc + 3] = v.w;
    }
    __syncthreads();
#pragma unroll
    for (int i = 0; i < 4; ++i) {
        const int oc = rr + 16 * i;  // WoT row (= Wo col)
        size_t off = (size_t)(c0 + oc) * (EE + DDIM) + r0 + 4 * cc;
        *(ushort4*)(thi + off) = make_ushort4((u16)bf16_rne(t[4 * cc + 0][oc]),
                                              (u16)bf16_rne(t[4 * cc + 1][oc]),
                                              (u16)bf16_rne(t[4 * cc + 2][oc]),
                                              (u16)bf16_rne(t[4 * cc + 3][oc]));
    }
}

// ---------------------------------------------------------------------------
// K1: decW = dec @ W_attn^T (NT, M=8192, N=1024, K=512) -> decW hi plane only.
// 2-MFMA: dec single-bf16 x Wa split (decW residual -> energy err ~0.026 std,
// well inside 0.5 tol). 64x64 block, BK=64 as 2x32 subtiles.
// ---------------------------------------------------------------------------
__global__ __launch_bounds__(256) void k_decw(const u16* __restrict__ Ahp,
                                              const u16* __restrict__ Bhp, const u16* __restrict__ Blp,
                                              u16* __restrict__ Chi) {
    __shared__ u16 Ah[2][BM2 * ROWU], Bh[2][BN * ROWU], Bl[2][BN * ROWU];
    const int tid = threadIdx.x;
    const int bm = blockIdx.x * BM2, bn = blockIdx.y * BN;  // x = m for B-tile L2 reuse
    f32x4 acc[2][2] = {};
    for (int k0 = 0; k0 < DDIM; k0 += 2 * BK) {
        __syncthreads();
        stage_glds<BM2>(Ah[0], Ahp + (size_t)bm * DDIM + k0, DDIM, tid);
        stage_glds<BM2>(Ah[1], Ahp + (size_t)bm * DDIM + k0 + BK, DDIM, tid);
        stage_glds<BN>(Bh[0], Bhp + (size_t)bn * DDIM + k0, DDIM, tid);
        stage_glds<BN>(Bl[0], Blp + (size_t)bn * DDIM + k0, DDIM, tid);
        stage_glds<BN>(Bh[1], Bhp + (size_t)bn * DDIM + k0 + BK, DDIM, tid);
        stage_glds<BN>(Bl[1], Blp + (size_t)bn * DDIM + k0 + BK, DDIM, tid);
        __builtin_amdgcn_s_waitcnt(0);
        __syncthreads();
        mfma_sb64(Ah[0], Bh[0], Bl[0], acc, tid);
        mfma_sb64(Ah[1], Bh[1], Bl[1], acc, tid);
    }
    const int lane = tid & 63, w = tid >> 6;
    const int wm = (w & 1) * 32, wn = (w >> 1) * 32;
    const int fr = lane & 15, q = lane >> 4;
#pragma unroll
    for (int j = 0; j < 2; ++j) {
        const int col = bn + wn + 16 * j + fr;
#pragma unroll
        for (int i = 0; i < 2; ++i)
#pragma unroll
            for (int r = 0; r < 4; ++r) {
                const int row = bm + wm + 16 * i + 4 * q + r;
                Chi[(size_t)row * EE + col] = (u16)bf16_rne(acc[i][j][r]);
            }
    }
}

// ---------------------------------------------------------------------------
// K1b: decb[m] = dec[m,:] . b_attn
// ---------------------------------------------------------------------------
__global__ __launch_bounds__(256) void k_decb(const float* __restrict__ dec,
                                              const float* __restrict__ ba,
                                              float* __restrict__ decb) {
    const int row = blockIdx.x * 4 + (threadIdx.x >> 6);
    const int lane = threadIdx.x & 63;
    const float* x = dec + (size_t)row * DDIM;
    float s = 0.f;
#pragma unroll
    for (int i = 0; i < 8; ++i) {
        int idx = lane + i * 64;
        s += x[idx] * ba[idx];
    }
#pragma unroll
    for (int off = 32; off >= 1; off >>= 1) s += __shfl_xor(s, off, 64);
    if (lane == 0) decb[row] = s;
}

// ---------------------------------------------------------------------------
// K2: masked energies (NT batched, M=T=128, N=S, K=E) + bias + mask
// 2-MFMA: decW single plane x enc split. 64x64 block, BK=64 subtiles.
// Energy err std ~0.036 -> max ~0.2 < 0.5 tolerance.
// ---------------------------------------------------------------------------
__global__ __launch_bounds__(256) void k_energy(const u16* __restrict__ Ahp,
                                                const float* __restrict__ enc,
                                                const int* __restrict__ mask,
                                                const float* __restrict__ decb,
                                                float* __restrict__ menerg) {
    const int b = blockIdx.z;
    const int bn = blockIdx.x * BN;
    const int bm = blockIdx.y * BM2;
    __shared__ u16 Ah[2][BM2 * ROWU];
    __shared__ unsigned Bh[2][BN * LDSTP], Bl[2][BN * LDSTP];
    const int tid = threadIdx.x;
    const u16* Abh = Ahp + (size_t)b * TT * EE + (size_t)bm * EE;
    const float* Bt = enc + (size_t)b * SS * EE + (size_t)bn * EE;
    f32x4 acc[2][2] = {};
    for (int k0 = 0; k0 < EE; k0 += 2 * BK) {
        __syncthreads();
        stage_glds<BM2>(Ah[0], Abh + k0, EE, tid);
        stage_glds<BM2>(Ah[1], Abh + k0 + BK, EE, tid);
        stage_nt<BN>(Bh[0], Bl[0], Bt + k0, EE, tid);
        stage_nt<BN>(Bh[1], Bl[1], Bt + k0 + BK, EE, tid);
        __builtin_amdgcn_s_waitcnt(0);
        __syncthreads();
        mfma_sbp64(Ah[0], Bh[0], Bl[0], acc, tid);
        mfma_sbp64(Ah[1], Bh[1], Bl[1], acc, tid);
    }
    const int lane = tid & 63, w = tid >> 6;
    const int wm = (w & 1) * 32, wn = (w >> 1) * 32;
    const int fr = lane & 15, q = lane >> 4;
    const int* mb = mask + (size_t)b * SS;
    const float* dbp = decb + (size_t)b * TT + bm;
    float* Crow = menerg + (size_t)b * TT * SS + (size_t)bm * SS;
    float db[2][4];
#pragma unroll
    for (int i = 0; i < 2; ++i) {
        float4 d4 = *(const float4*)(dbp + wm + 16 * i + 4 * q);
        db[i][0] = d4.x; db[i][1] = d4.y; db[i][2] = d4.z; db[i][3] = d4.w;
    }
#pragma unroll
    for (int j = 0; j < 2; ++j) {
        const int col = bn + wn + 16 * j + fr;
        const int mk = mb[col];
#pragma unroll
        for (int i = 0; i < 2; ++i)
#pragma unroll
            for (int r = 0; r < 4; ++r) {
                const int row = wm + 16 * i + 4 * q + r;
                Crow[(size_t)row * SS + col] = mk ? acc[i][j][r] + db[i][r] : NEG_INF_F;
            }
    }
}

// ---------------------------------------------------------------------------
// K3: softmax over S=512 -> attn fp32 (output) + attn hi plane (bf16 rne)
// ---------------------------------------------------------------------------
__global__ __launch_bounds__(128) void k_softmax(const float* __restrict__ me,
                                                 float* __restrict__ attn,
                                                 u16* __restrict__ ahi) {
    const int row = blockIdx.x;
    const int tid = threadIdx.x;
    const float4 v = ((const float4*)(me + (size_t)row * SS))[tid];
    float m = fmaxf(fmaxf(v.x, v.y), fmaxf(v.z, v.w));
#pragma unroll
    for (int off = 32; off >= 1; off >>= 1) m = fmaxf(m, __shfl_xor(m, off, 64));
    __shared__ float redm[2];
    __shared__ float reds[2];
    const int wv = tid >> 6, lane = tid & 63;
    if (lane == 0) redm[wv] = m;
    __syncthreads();
    m = fmaxf(redm[0], redm[1]);
    float e0 = __expf(v.x - m), e1 = __expf(v.y - m);
    float e2 = __expf(v.z - m), e3 = __expf(v.w - m);
    float s = (e0 + e1) + (e2 + e3);
#pragma unroll
    for (int off = 32; off >= 1; off >>= 1) s += __shfl_xor(s, off, 64);
    if (lane == 0) reds[wv] = s;
    __syncthreads();
    s = reds[0] + reds[1];
    const float inv = 1.0f / s;
    float o0 = e0 * inv, o1 = e1 * inv, o2 = e2 * inv, o3 = e3 * inv;
    ((float4*)(attn + (size_t)row * SS))[tid] = make_float4(o0, o1, o2, o3);
    ((ushort4*)(ahi + (size_t)row * SS))[tid] =
        make_ushort4((u16)bf16_rne(o0), (u16)bf16_rne(o1),
                     (u16)bf16_rne(o2), (u16)bf16_rne(o3));
}

// ---------------------------------------------------------------------------
// K4: wc = attn @ enc (NN batched, M=T, N=E, K=S) -> wc hi plane ONLY.
// Single-bf16 operands. 1 MFMA per tile, BK=64 subtiles.
// ---------------------------------------------------------------------------
__global__ __launch_bounds__(256) void k_ctx(const u16* __restrict__ Ahp,
                                             const float* __restrict__ enc,
                                             u16* __restrict__ Chi) {
    const int b = blockIdx.z;
    const int bn = blockIdx.x * BN;  // over E
    __shared__ u16 Ah[2][BM * ROWU];
    __shared__ unsigned Bh[2][BN * LDSTP];
    const int tid = threadIdx.x;
    const u16* Abh = Ahp + (size_t)b * TT * SS;
    const float* Bm = enc + (size_t)b * SS * EE + bn;
    f32x4 acc[4][2] = {};
    for (int k0 = 0; k0 < SS; k0 += 2 * BK) {
        __syncthreads();
        stage_glds<BM>(Ah[0], Abh + k0, SS, tid);
        stage_glds<BM>(Ah[1], Abh + k0 + BK, SS, tid);
        stage_tr1(Bh[0], Bm + (size_t)k0 * EE, EE, tid);
        stage_tr1(Bh[1], Bm + (size_t)(k0 + BK) * EE, EE, tid);
        __builtin_amdgcn_s_waitcnt(0);
        __syncthreads();
        mfma_sp1(Ah[0], Bh[0], acc, tid);
        mfma_sp1(Ah[1], Bh[1], acc, tid);
    }
    const int lane = tid & 63, w = tid >> 6;
    const int wm = (w & 1) * 64, wn = (w >> 1) * 32;
    const int fr = lane & 15, q = lane >> 4;
    u16* Ch = Chi + (size_t)b * TT * EE;
#pragma unroll
    for (int j = 0; j < 2; ++j) {
        const int col = bn + wn + 16 * j + fr;
#pragma unroll
        for (int i = 0; i < 4; ++i)
#pragma unroll
            for (int r = 0; r < 4; ++r) {
                const int row = wm + 16 * i + 4 * q + r;
                Ch[(size_t)row * EE + col] = (u16)bf16_rne(acc[i][j][r]);
            }
    }
}

// ---------------------------------------------------------------------------
// K5: h_tilde = tanh([wc | dec] @ W_out), ALL-SINGLE-bf16. BK=64.
// ---------------------------------------------------------------------------
__global__ __launch_bounds__(256) void k_out(const u16* __restrict__ wch,
                                             const u16* __restrict__ dech,
                                             const u16* __restrict__ woth,
                                             float* __restrict__ ht) {
    __shared__ u16 Ah[2][BM * ROWU], Bh[2][BN * ROWU];
    const int tid = threadIdx.x;
    const int bm = blockIdx.x * BM, bn = blockIdx.y * BN;  // x = m for B-tile reuse
    const int KTOT = EE + DDIM;
    f32x4 acc[4][2] = {};
    for (int k0 = 0; k0 < KTOT; k0 += 2 * BK) {
        __syncthreads();
#pragma unroll
        for (int s = 0; s < 2; ++s) {
            const int kk = k0 + BK * s;
            const u16* ah;
            int ld;
            if (kk < EE) {
                ah = wch + (size_t)bm * EE + kk;
                ld = EE;
            } else {
                ah = dech + (size_t)bm * DDIM + (kk - EE);
                ld = DDIM;
            }
            stage_glds<BM>(Ah[s], ah, ld, tid);
            stage_glds<BN>(Bh[s], woth + (size_t)bn * KTOT + kk, KTOT, tid);
        }
        __builtin_amdgcn_s_waitcnt(0);
        __syncthreads();
        mfma_s1(Ah[0], Bh[0], acc, tid);
        mfma_s1(Ah[1], Bh[1], acc, tid);
    }
    const int lane = tid & 63, w = tid >> 6;
    const int wm = (w & 1) * 64, wn = (w >> 1) * 32;
    const int fr = lane & 15, q = lane >> 4;
#pragma unroll
    for (int j = 0; j < 2; ++j) {
        const int col = bn + wn + 16 * j + fr;
#pragma unroll
        for (int i = 0; i < 4; ++i)
#pragma unroll
            for (int r = 0; r < 4; ++r) {
                const int row = bm + wm + 16 * i + 4 * q + r;
                ht[(size_t)row * DDIM + col] = fast_tanh(acc[i][j][r]);
            }
    }
}

// ---------------------------------------------------------------------------
extern "C" void kernel_launch(void* const* d_in, const int* in_sizes, int n_in,
                              void* d_out, int out_size, void* d_ws, size_t ws_size,
                              hipStream_t stream) {
    (void)in_sizes; (void)n_in; (void)out_size; (void)ws_size;
    const float* dec = (const float*)d_in[0];
    const float* enc = (const float*)d_in[1];
    const int* mask = (const int*)d_in[2];
    const float* Wa = (const float*)d_in[3];
    const float* ba = (const float*)d_in[4];
    const float* Wo = (const float*)d_in[5];

    float* h_tilde = (float*)d_out;
    float* attn = h_tilde + (size_t)BB * TT * DDIM;
    float* menerg = attn + (size_t)BB * TT * SS;

    // Workspace layout (bytes)
    char* ws = (char*)d_ws;
    u16* decW_hi = (u16*)(ws);                       // 8192x1024 u16 = 16.78 MB
    u16* dec_hi  = (u16*)(ws + 33554432);            // 8192x512
    u16* attn_hi = (u16*)(ws + 50331648);            // 8192x512
    u16* wa_hi   = (u16*)(ws + 67108864);            // 1024x512
    u16* wa_lo   = (u16*)(ws + 68157440);
    u16* wot_hi  = (u16*)(ws + 69206016);            // 512x1536
    float* decb  = (float*)(ws + 72351744);          // 8192 f32
    // wc plane aliases decW_hi (decW dead after k_energy)
    u16* wc_hi = decW_hi;

    k_conv1<<<(BB * TT * DDIM) / 4 / 256, 256, 0, stream>>>(dec, dec_hi);
    k_conv<<<(EE * DDIM) / 4 / 256, 256, 0, stream>>>(Wa, wa_hi, wa_lo);
    k_wot<<<dim3((EE + DDIM) / 64, DDIM / 64), 256, 0, stream>>>(Wo, wot_hi);
    k_decb<<<(BB * TT) / 4, 256, 0, stream>>>(dec, ba, decb);
    k_decw<<<dim3((BB * TT) / BM2, EE / BN), 256, 0, stream>>>(dec_hi, wa_hi, wa_lo, decW_hi);
    k_energy<<<dim3(SS / BN, TT / BM2, BB), 256, 0, stream>>>(decW_hi, enc, mask, decb, menerg);
    k_softmax<<<BB * TT, 128, 0, stream>>>(menerg, attn, attn_hi);
    k_ctx<<<dim3(EE / BN, 1, BB), 256, 0, stream>>>(attn_hi, enc, wc_hi);
    k_out<<<dim3((BB * TT) / BM, DDIM / BN), 256, 0, stream>>>(wc_hi, dec_hi, wot_hi, h_tilde);
}

// Round 7
// 328.433 us; speedup vs baseline: 1.3719x; 1.0291x over previous
//
#include <hip/hip_runtime.h>
#include <cmath>

// Problem constants
#define BB 64
#define TT 128
#define SS 512
#define EE 1024
#define DDIM 512
#define NEG_INF_F (-1.0e10f)

// MFMA tiling
#define BM 128
#define BM2 64   // half-height block (wave tile 32x32)
#define BN 64
#define BK 32
#define LDSTP 20   // padded layout row stride (dwords): 80 B rows -> b128-aligned, 2-way banks (free)
#define ROWU 32    // swizzled plane layout row stride in u16 (64 B/row)

typedef unsigned short u16;
typedef __attribute__((ext_vector_type(8))) short bf16x8;
typedef __attribute__((ext_vector_type(4))) float f32x4;

// ---------------------------------------------------------------------------
// fp32 -> bf16 rne
// ---------------------------------------------------------------------------
__device__ __forceinline__ unsigned bf16_rne(float f) {
    unsigned u = __float_as_uint(f);
    return (u + 0x7fffu + ((u >> 16) & 1u)) >> 16;
}

// Overflow-safe fast tanh: t = e^{-2|x|} in (0,1], r = (1-t)/(1+t)
__device__ __forceinline__ float fast_tanh(float x) {
    float t = __expf(-2.0f * fabsf(x));
    float r = __fdividef(1.0f - t, 1.0f + t);
    return copysignf(r, x);
}

// ---------------------------------------------------------------------------
// glds staging of a bf16 plane tile: ROWS rows x 32 bf16 (64 B/row), with the
// quad-swizzle chunk(q)->slot q^((r>>1)&3). Lane-linear LDS writes (16 B/lane).
// ---------------------------------------------------------------------------
template <int ROWS>
__device__ __forceinline__ void stage_glds(u16* lds, const u16* __restrict__ src,
                                           int ld, int tid) {
    const int w = tid >> 6, lane = tid & 63;
    const int rl = lane >> 2, p = lane & 3;
#pragma unroll
    for (int i = 0; i < ROWS / 64; ++i) {
        const int r0 = (w + 4 * i) * 16;
        const int r = r0 + rl;
        const int q = p ^ ((r >> 1) & 3);
        const u16* g = src + (size_t)r * ld + 8 * q;
        __builtin_amdgcn_global_load_lds(
            (const __attribute__((address_space(1))) unsigned*)g,
            (__attribute__((address_space(3))) unsigned*)(lds + r0 * ROWU),
            16, 0, 0);
    }
}

// Read a 16x16x32 fragment from the swizzled plane layout (one ds_read_b128)
__device__ __forceinline__ bf16x8 read_frag_sw(const u16* buf, int row, int q) {
    const int c = q ^ ((row >> 1) & 3);
    return *(const bf16x8*)(buf + row * ROWU + 8 * c);
}

// ---------------------------------------------------------------------------
// Single-plane VALU staging of an NT fp32 operand (rows x BK, k contiguous)
// into padded LDS (u32 = bf16 pair (2k,2k+1)), rne only. enc in k_energy.
// ---------------------------------------------------------------------------
template <int ROWS>
__device__ __forceinline__ void stage_nt1(unsigned* hi,
                                          const float* __restrict__ src, int ld, int tid) {
#pragma unroll
    for (int i = 0; i < ROWS / 32; ++i) {
        int s = tid + 256 * i;
        int r = s >> 3, kq = s & 7;
        float4 v = *(const float4*)(src + (size_t)r * ld + 4 * kq);
        *(uint2*)&hi[r * LDSTP + 2 * kq] =
            make_uint2(bf16_rne(v.x) | (bf16_rne(v.y) << 16),
                       bf16_rne(v.z) | (bf16_rne(v.w) << 16));
    }
}

// ---------------------------------------------------------------------------
// Single-plane VALU staging of a transposed fp32 B tile (k_ctx, 32 k-rows):
// global [32 k][BN n] -> padded LDS rows = n, bf16 rne only.
// ---------------------------------------------------------------------------
__device__ __forceinline__ void stage_tr1(unsigned* hi, const float* __restrict__ src,
                                          int ld, int tid) {
    int eq = tid & 15;   // n quad
    int sp = tid >> 4;   // k pair
    const float* p = src + (size_t)(2 * sp) * ld + 4 * eq;
    float4 va = *(const float4*)p;
    float4 vb = *(const float4*)(p + ld);
    float av[4] = {va.x, va.y, va.z, va.w};
    float bv[4] = {vb.x, vb.y, vb.z, vb.w};
#pragma unroll
    for (int c = 0; c < 4; ++c) {
        hi[(4 * eq + c) * LDSTP + sp] = bf16_rne(av[c]) | (bf16_rne(bv[c]) << 16);
    }
}

// Read a fragment from the padded layout (aligned b128: 80r+16q bytes)
__device__ __forceinline__ bf16x8 read_frag_pad(const unsigned* buf, int row, int q) {
    return *(const bf16x8*)(buf + row * LDSTP + 4 * q);
}

// ---------------------------------------------------------------------------
// MFMA cores (all single-bf16 operands now)
// ---------------------------------------------------------------------------
// 64x64 block, single A (sw) x single B (sw) — k_decw
__device__ __forceinline__ void mfma_ss1_64(const u16* Ah, const u16* Bh,
                                            f32x4 acc[2][2], int tid) {
    const int lane = tid & 63, w = tid >> 6;
    const int wm = (w & 1) * 32, wn = (w >> 1) * 32;
    const int fr = lane & 15, q = lane >> 4;
    bf16x8 ah[2];
#pragma unroll
    for (int i = 0; i < 2; ++i) ah[i] = read_frag_sw(Ah, wm + 16 * i + fr, q);
#pragma unroll
    for (int j = 0; j < 2; ++j) {
        bf16x8 bh = read_frag_sw(Bh, wn + 16 * j + fr, q);
#pragma unroll
        for (int i = 0; i < 2; ++i)
            acc[i][j] = __builtin_amdgcn_mfma_f32_16x16x32_bf16(ah[i], bh, acc[i][j], 0, 0, 0);
    }
}

// 64x64 block, single A (sw) x single B (padded) — k_energy
__device__ __forceinline__ void mfma_sbp1_64(const u16* Ah, const unsigned* Bh,
                                             f32x4 acc[2][2], int tid) {
    const int lane = tid & 63, w = tid >> 6;
    const int wm = (w & 1) * 32, wn = (w >> 1) * 32;
    const int fr = lane & 15, q = lane >> 4;
    bf16x8 ah[2];
#pragma unroll
    for (int i = 0; i < 2; ++i) ah[i] = read_frag_sw(Ah, wm + 16 * i + fr, q);
#pragma unroll
    for (int j = 0; j < 2; ++j) {
        bf16x8 bh = read_frag_pad(Bh, wn + 16 * j + fr, q);
#pragma unroll
        for (int i = 0; i < 2; ++i)
            acc[i][j] = __builtin_amdgcn_mfma_f32_16x16x32_bf16(ah[i], bh, acc[i][j], 0, 0, 0);
    }
}

// 128x64 block, single A (sw) x single B (padded) — k_ctx
__device__ __forceinline__ void mfma_sp1(const u16* Ah, const unsigned* Bh,
                                         f32x4 acc[4][2], int tid) {
    const int lane = tid & 63, w = tid >> 6;
    const int wm = (w & 1) * 64, wn = (w >> 1) * 32;
    const int fr = lane & 15, q = lane >> 4;
    bf16x8 ah[4];
#pragma unroll
    for (int i = 0; i < 4; ++i) ah[i] = read_frag_sw(Ah, wm + 16 * i + fr, q);
#pragma unroll
    for (int j = 0; j < 2; ++j) {
        bf16x8 bh = read_frag_pad(Bh, wn + 16 * j + fr, q);
#pragma unroll
        for (int i = 0; i < 4; ++i)
            acc[i][j] = __builtin_amdgcn_mfma_f32_16x16x32_bf16(ah[i], bh, acc[i][j], 0, 0, 0);
    }
}

// 128x64 block, single A (sw) x single B (sw) — k_out
__device__ __forceinline__ void mfma_s1(const u16* Ah, const u16* Bh,
                                        f32x4 acc[4][2], int tid) {
    const int lane = tid & 63, w = tid >> 6;
    const int wm = (w & 1) * 64, wn = (w >> 1) * 32;
    const int fr = lane & 15, q = lane >> 4;
    bf16x8 ah[4];
#pragma unroll
    for (int i = 0; i < 4; ++i) ah[i] = read_frag_sw(Ah, wm + 16 * i + fr, q);
#pragma unroll
    for (int j = 0; j < 2; ++j) {
        bf16x8 bh = read_frag_sw(Bh, wn + 16 * j + fr, q);
#pragma unroll
        for (int i = 0; i < 4; ++i)
            acc[i][j] = __builtin_amdgcn_mfma_f32_16x16x32_bf16(ah[i], bh, acc[i][j], 0, 0, 0);
    }
}

// ---------------------------------------------------------------------------
// Convert kernels
// ---------------------------------------------------------------------------
// fp32 -> single bf16 hi plane (dec, Wa)
__global__ __launch_bounds__(256) void k_conv1(const float* __restrict__ src,
                                               u16* __restrict__ hi) {
    const int i = blockIdx.x * 256 + threadIdx.x;
    float4 v = ((const float4*)src)[i];
    ((ushort4*)hi)[i] = make_ushort4((u16)bf16_rne(v.x), (u16)bf16_rne(v.y),
                                     (u16)bf16_rne(v.z), (u16)bf16_rne(v.w));
}

// Wo [1536,512] -> WoT hi plane [512,1536]
__global__ __launch_bounds__(256) void k_wot(const float* __restrict__ Wo,
                                             u16* __restrict__ thi) {
    __shared__ float t[64][65];
    const int tid = threadIdx.x;
    const int r0 = blockIdx.x * 64;  // Wo row tile (k)
    const int c0 = blockIdx.y * 64;  // Wo col tile (n)
    const int rr = tid >> 4, cc = tid & 15;
#pragma unroll
    for (int i = 0; i < 4; ++i) {
        float4 v = *(const float4*)(Wo + (size_t)(r0 + rr + 16 * i) * DDIM + c0 + 4 * cc);
        t[rr + 16 * i][4 * cc + 0] = v.x;
        t[rr + 16 * i][4 * cc + 1] = v.y;
        t[rr + 16 * i][4 * cc + 2] = v.z;
        t[rr + 16 * i][4 * cc + 3] = v.w;
    }
    __syncthreads();
#pragma unroll
    for (int i = 0; i < 4; ++i) {
        const int oc = rr + 16 * i;  // WoT row (= Wo col)
        size_t off = (size_t)(c0 + oc) * (EE + DDIM) + r0 + 4 * cc;
        *(ushort4*)(thi + off) = make_ushort4((u16)bf16_rne(t[4 * cc + 0][oc]),
                                              (u16)bf16_rne(t[4 * cc + 1][oc]),
                                              (u16)bf16_rne(t[4 * cc + 2][oc]),
                                              (u16)bf16_rne(t[4 * cc + 3][oc]));
    }
}

// ---------------------------------------------------------------------------
// K1: decW = dec @ W_attn^T (NT, M=8192, N=1024, K=512) -> decW hi plane.
// ALL-SINGLE bf16 (dec, Wa, decW each contribute ~0.026 std to the final
// energies; total budget ~0.052 std, max ~0.26 < 0.5 tol). 1 MFMA/tile.
// ---------------------------------------------------------------------------
__global__ __launch_bounds__(256) void k_decw(const u16* __restrict__ Ahp,
                                              const u16* __restrict__ Bhp,
                                              u16* __restrict__ Chi) {
    __shared__ u16 Ah[2][BM2 * ROWU], Bh[2][BN * ROWU];
    const int tid = threadIdx.x;
    const int bm = blockIdx.x * BM2, bn = blockIdx.y * BN;  // x = m for B-tile L2 reuse
    f32x4 acc[2][2] = {};
    for (int k0 = 0; k0 < DDIM; k0 += 2 * BK) {
        __syncthreads();
        stage_glds<BM2>(Ah[0], Ahp + (size_t)bm * DDIM + k0, DDIM, tid);
        stage_glds<BM2>(Ah[1], Ahp + (size_t)bm * DDIM + k0 + BK, DDIM, tid);
        stage_glds<BN>(Bh[0], Bhp + (size_t)bn * DDIM + k0, DDIM, tid);
        stage_glds<BN>(Bh[1], Bhp + (size_t)bn * DDIM + k0 + BK, DDIM, tid);
        __builtin_amdgcn_s_waitcnt(0);
        __syncthreads();
        mfma_ss1_64(Ah[0], Bh[0], acc, tid);
        mfma_ss1_64(Ah[1], Bh[1], acc, tid);
    }
    const int lane = tid & 63, w = tid >> 6;
    const int wm = (w & 1) * 32, wn = (w >> 1) * 32;
    const int fr = lane & 15, q = lane >> 4;
#pragma unroll
    for (int j = 0; j < 2; ++j) {
        const int col = bn + wn + 16 * j + fr;
#pragma unroll
        for (int i = 0; i < 2; ++i)
#pragma unroll
            for (int r = 0; r < 4; ++r) {
                const int row = bm + wm + 16 * i + 4 * q + r;
                Chi[(size_t)row * EE + col] = (u16)bf16_rne(acc[i][j][r]);
            }
    }
}

// ---------------------------------------------------------------------------
// K1b: decb[m] = dec[m,:] . b_attn
// ---------------------------------------------------------------------------
__global__ __launch_bounds__(256) void k_decb(const float* __restrict__ dec,
                                              const float* __restrict__ ba,
                                              float* __restrict__ decb) {
    const int row = blockIdx.x * 4 + (threadIdx.x >> 6);
    const int lane = threadIdx.x & 63;
    const float* x = dec + (size_t)row * DDIM;
    float s = 0.f;
#pragma unroll
    for (int i = 0; i < 8; ++i) {
        int idx = lane + i * 64;
        s += x[idx] * ba[idx];
    }
#pragma unroll
    for (int off = 32; off >= 1; off >>= 1) s += __shfl_xor(s, off, 64);
    if (lane == 0) decb[row] = s;
}

// ---------------------------------------------------------------------------
// K2: masked energies (NT batched, M=T=128, N=S, K=E) + bias + mask
// decW single (glds) x enc single (stage_nt1, rne only). 1 MFMA/tile.
// LDS 18 KB -> high occupancy. BK=64 as 2x32 subtiles.
// ---------------------------------------------------------------------------
__global__ __launch_bounds__(256) void k_energy(const u16* __restrict__ Ahp,
                                                const float* __restrict__ enc,
                                                const int* __restrict__ mask,
                                                const float* __restrict__ decb,
                                                float* __restrict__ menerg) {
    const int b = blockIdx.z;
    const int bn = blockIdx.x * BN;
    const int bm = blockIdx.y * BM2;
    __shared__ u16 Ah[2][BM2 * ROWU];
    __shared__ unsigned Bh[2][BN * LDSTP];
    const int tid = threadIdx.x;
    const u16* Abh = Ahp + (size_t)b * TT * EE + (size_t)bm * EE;
    const float* Bt = enc + (size_t)b * SS * EE + (size_t)bn * EE;
    f32x4 acc[2][2] = {};
    for (int k0 = 0; k0 < EE; k0 += 2 * BK) {
        __syncthreads();
        stage_glds<BM2>(Ah[0], Abh + k0, EE, tid);
        stage_glds<BM2>(Ah[1], Abh + k0 + BK, EE, tid);
        stage_nt1<BN>(Bh[0], Bt + k0, EE, tid);
        stage_nt1<BN>(Bh[1], Bt + k0 + BK, EE, tid);
        __builtin_amdgcn_s_waitcnt(0);
        __syncthreads();
        mfma_sbp1_64(Ah[0], Bh[0], acc, tid);
        mfma_sbp1_64(Ah[1], Bh[1], acc, tid);
    }
    const int lane = tid & 63, w = tid >> 6;
    const int wm = (w & 1) * 32, wn = (w >> 1) * 32;
    const int fr = lane & 15, q = lane >> 4;
    const int* mb = mask + (size_t)b * SS;
    const float* dbp = decb + (size_t)b * TT + bm;
    float* Crow = menerg + (size_t)b * TT * SS + (size_t)bm * SS;
    float db[2][4];
#pragma unroll
    for (int i = 0; i < 2; ++i) {
        float4 d4 = *(const float4*)(dbp + wm + 16 * i + 4 * q);
        db[i][0] = d4.x; db[i][1] = d4.y; db[i][2] = d4.z; db[i][3] = d4.w;
    }
#pragma unroll
    for (int j = 0; j < 2; ++j) {
        const int col = bn + wn + 16 * j + fr;
        const int mk = mb[col];
#pragma unroll
        for (int i = 0; i < 2; ++i)
#pragma unroll
            for (int r = 0; r < 4; ++r) {
                const int row = wm + 16 * i + 4 * q + r;
                Crow[(size_t)row * SS + col] = mk ? acc[i][j][r] + db[i][r] : NEG_INF_F;
            }
    }
}

// ---------------------------------------------------------------------------
// K3: softmax over S=512 -> attn fp32 (output) + attn hi plane (bf16 rne)
// ---------------------------------------------------------------------------
__global__ __launch_bounds__(128) void k_softmax(const float* __restrict__ me,
                                                 float* __restrict__ attn,
                                                 u16* __restrict__ ahi) {
    const int row = blockIdx.x;
    const int tid = threadIdx.x;
    const float4 v = ((const float4*)(me + (size_t)row * SS))[tid];
    float m = fmaxf(fmaxf(v.x, v.y), fmaxf(v.z, v.w));
#pragma unroll
    for (int off = 32; off >= 1; off >>= 1) m = fmaxf(m, __shfl_xor(m, off, 64));
    __shared__ float redm[2];
    __shared__ float reds[2];
    const int wv = tid >> 6, lane = tid & 63;
    if (lane == 0) redm[wv] = m;
    __syncthreads();
    m = fmaxf(redm[0], redm[1]);
    float e0 = __expf(v.x - m), e1 = __expf(v.y - m);
    float e2 = __expf(v.z - m), e3 = __expf(v.w - m);
    float s = (e0 + e1) + (e2 + e3);
#pragma unroll
    for (int off = 32; off >= 1; off >>= 1) s += __shfl_xor(s, off, 64);
    if (lane == 0) reds[wv] = s;
    __syncthreads();
    s = reds[0] + reds[1];
    const float inv = 1.0f / s;
    float o0 = e0 * inv, o1 = e1 * inv, o2 = e2 * inv, o3 = e3 * inv;
    ((float4*)(attn + (size_t)row * SS))[tid] = make_float4(o0, o1, o2, o3);
    ((ushort4*)(ahi + (size_t)row * SS))[tid] =
        make_ushort4((u16)bf16_rne(o0), (u16)bf16_rne(o1),
                     (u16)bf16_rne(o2), (u16)bf16_rne(o3));
}

// ---------------------------------------------------------------------------
// K4: wc = attn @ enc (NN batched, M=T, N=E, K=S) -> wc hi plane.
// Single-bf16 operands. 1 MFMA per tile, BK=64 subtiles.
// ---------------------------------------------------------------------------
__global__ __launch_bounds__(256) void k_ctx(const u16* __restrict__ Ahp,
                                             const float* __restrict__ enc,
                                             u16* __restrict__ Chi) {
    const int b = blockIdx.z;
    const int bn = blockIdx.x * BN;  // over E
    __shared__ u16 Ah[2][BM * ROWU];
    __shared__ unsigned Bh[2][BN * LDSTP];
    const int tid = threadIdx.x;
    const u16* Abh = Ahp + (size_t)b * TT * SS;
    const float* Bm = enc + (size_t)b * SS * EE + bn;
    f32x4 acc[4][2] = {};
    for (int k0 = 0; k0 < SS; k0 += 2 * BK) {
        __syncthreads();
        stage_glds<BM>(Ah[0], Abh + k0, SS, tid);
        stage_glds<BM>(Ah[1], Abh + k0 + BK, SS, tid);
        stage_tr1(Bh[0], Bm + (size_t)k0 * EE, EE, tid);
        stage_tr1(Bh[1], Bm + (size_t)(k0 + BK) * EE, EE, tid);
        __builtin_amdgcn_s_waitcnt(0);
        __syncthreads();
        mfma_sp1(Ah[0], Bh[0], acc, tid);
        mfma_sp1(Ah[1], Bh[1], acc, tid);
    }
    const int lane = tid & 63, w = tid >> 6;
    const int wm = (w & 1) * 64, wn = (w >> 1) * 32;
    const int fr = lane & 15, q = lane >> 4;
    u16* Ch = Chi + (size_t)b * TT * EE;
#pragma unroll
    for (int j = 0; j < 2; ++j) {
        const int col = bn + wn + 16 * j + fr;
#pragma unroll
        for (int i = 0; i < 4; ++i)
#pragma unroll
            for (int r = 0; r < 4; ++r) {
                const int row = wm + 16 * i + 4 * q + r;
                Ch[(size_t)row * EE + col] = (u16)bf16_rne(acc[i][j][r]);
            }
    }
}

// ---------------------------------------------------------------------------
// K5: h_tilde = tanh([wc | dec] @ W_out), ALL-SINGLE-bf16. BK=64.
// ---------------------------------------------------------------------------
__global__ __launch_bounds__(256) void k_out(const u16* __restrict__ wch,
                                             const u16* __restrict__ dech,
                                             const u16* __restrict__ woth,
                                             float* __restrict__ ht) {
    __shared__ u16 Ah[2][BM * ROWU], Bh[2][BN * ROWU];
    const int tid = threadIdx.x;
    const int bm = blockIdx.x * BM, bn = blockIdx.y * BN;  // x = m for B-tile reuse
    const int KTOT = EE + DDIM;
    f32x4 acc[4][2] = {};
    for (int k0 = 0; k0 < KTOT; k0 += 2 * BK) {
        __syncthreads();
#pragma unroll
        for (int s = 0; s < 2; ++s) {
            const int kk = k0 + BK * s;
            const u16* ah;
            int ld;
            if (kk < EE) {
                ah = wch + (size_t)bm * EE + kk;
                ld = EE;
            } else {
                ah = dech + (size_t)bm * DDIM + (kk - EE);
                ld = DDIM;
            }
            stage_glds<BM>(Ah[s], ah, ld, tid);
            stage_glds<BN>(Bh[s], woth + (size_t)bn * KTOT + kk, KTOT, tid);
        }
        __builtin_amdgcn_s_waitcnt(0);
        __syncthreads();
        mfma_s1(Ah[0], Bh[0], acc, tid);
        mfma_s1(Ah[1], Bh[1], acc, tid);
    }
    const int lane = tid & 63, w = tid >> 6;
    const int wm = (w & 1) * 64, wn = (w >> 1) * 32;
    const int fr = lane & 15, q = lane >> 4;
#pragma unroll
    for (int j = 0; j < 2; ++j) {
        const int col = bn + wn + 16 * j + fr;
#pragma unroll
        for (int i = 0; i < 4; ++i)
#pragma unroll
            for (int r = 0; r < 4; ++r) {
                const int row = bm + wm + 16 * i + 4 * q + r;
                ht[(size_t)row * DDIM + col] = fast_tanh(acc[i][j][r]);
            }
    }
}

// ---------------------------------------------------------------------------
extern "C" void kernel_launch(void* const* d_in, const int* in_sizes, int n_in,
                              void* d_out, int out_size, void* d_ws, size_t ws_size,
                              hipStream_t stream) {
    (void)in_sizes; (void)n_in; (void)out_size; (void)ws_size;
    const float* dec = (const float*)d_in[0];
    const float* enc = (const float*)d_in[1];
    const int* mask = (const int*)d_in[2];
    const float* Wa = (const float*)d_in[3];
    const float* ba = (const float*)d_in[4];
    const float* Wo = (const float*)d_in[5];

    float* h_tilde = (float*)d_out;
    float* attn = h_tilde + (size_t)BB * TT * DDIM;
    float* menerg = attn + (size_t)BB * TT * SS;

    // Workspace layout (bytes)
    char* ws = (char*)d_ws;
    u16* decW_hi = (u16*)(ws);                       // 8192x1024 u16 = 16.78 MB
    u16* dec_hi  = (u16*)(ws + 33554432);            // 8192x512
    u16* attn_hi = (u16*)(ws + 50331648);            // 8192x512
    u16* wa_hi   = (u16*)(ws + 67108864);            // 1024x512
    u16* wot_hi  = (u16*)(ws + 69206016);            // 512x1536
    float* decb  = (float*)(ws + 72351744);          // 8192 f32
    // wc plane aliases decW_hi (decW dead after k_energy)
    u16* wc_hi = decW_hi;

    k_conv1<<<(BB * TT * DDIM) / 4 / 256, 256, 0, stream>>>(dec, dec_hi);
    k_conv1<<<(EE * DDIM) / 4 / 256, 256, 0, stream>>>(Wa, wa_hi);
    k_wot<<<dim3((EE + DDIM) / 64, DDIM / 64), 256, 0, stream>>>(Wo, wot_hi);
    k_decb<<<(BB * TT) / 4, 256, 0, stream>>>(dec, ba, decb);
    k_decw<<<dim3((BB * TT) / BM2, EE / BN), 256, 0, stream>>>(dec_hi, wa_hi, decW_hi);
    k_energy<<<dim3(SS / BN, TT / BM2, BB), 256, 0, stream>>>(decW_hi, enc, mask, decb, menerg);
    k_softmax<<<BB * TT, 128, 0, stream>>>(menerg, attn, attn_hi);
    k_ctx<<<dim3(EE / BN, 1, BB), 256, 0, stream>>>(attn_hi, enc, wc_hi);
    k_out<<<dim3((BB * TT) / BM, DDIM / BN), 256, 0, stream>>>(wc_hi, dec_hi, wot_hi, h_tilde);
}